// Round 2
// baseline (1253.062 us; speedup 1.0000x reference)
//
#include <hip/hip_runtime.h>

typedef unsigned int u32;
typedef unsigned short u16;
typedef __attribute__((ext_vector_type(8))) short short8;
typedef __attribute__((ext_vector_type(4))) float f32x4;

__device__ __forceinline__ float b2f(u16 h){ u32 x = ((u32)h) << 16; return __builtin_bit_cast(float, x); }
__device__ __forceinline__ u16 f2b(float f){
  u32 x = __builtin_bit_cast(u32, f);
  x += 0x7fffu + ((x >> 16) & 1u);
  return (u16)(x >> 16);
}
#define LOH(u) ((u16)((u) & 0xffffu))
#define HIH(u) ((u16)((u) >> 16))

__device__ __forceinline__ void gload16(const u16* g, u16* lds){
  __builtin_amdgcn_global_load_lds((const __attribute__((address_space(1))) u32*)g,
                                   (__attribute__((address_space(3))) u32*)lds, 16, 0, 0);
}

// ---------------------------------------------------------------------------
// Generic MFMA GEMM: C[M,N] = A[M,K] * B[N,K]^T   (A,B bf16 K-contiguous)
// 128x128 tile, BK=32, 256 threads (4 waves 2x2), 16x16x32 bf16 MFMA.
// EPI: 0 bf16, 1 tanh bf16, 2 token-mix bf16 (e_x,e_vec f32), 3 decay f32,
//      4 silu bf16, 5 plain f32
// ---------------------------------------------------------------------------
template<int EPI>
__global__ __launch_bounds__(256) void gemm_bt(
    const u16* __restrict__ A, int lda,
    const u16* __restrict__ B, int ldb,
    void* __restrict__ Cv, int ldc, int K,
    const float* __restrict__ e_x, const float* __restrict__ e_vec)
{
  __shared__ u16 As[4096];
  __shared__ u16 Bs[4096];
  const int tid = threadIdx.x;
  const int wave = tid >> 6, lane = tid & 63;
  const int wr = wave >> 1, wc = wave & 1;
  const int l16 = lane & 15, kq = lane >> 4;
  const long row0 = (long)blockIdx.x * 128;
  const long col0 = (long)blockIdx.y * 128;

  f32x4 acc[4][4];
#pragma unroll
  for (int i = 0; i < 4; i++)
#pragma unroll
    for (int j = 0; j < 4; j++) acc[i][j] = (f32x4)0.0f;

  const int c0 = tid, c1 = tid + 256;
  const u16* Ag0 = A + (row0 + (c0 >> 2)) * (long)lda + (c0 & 3) * 8;
  const u16* Ag1 = A + (row0 + (c1 >> 2)) * (long)lda + (c1 & 3) * 8;
  const u16* Bg0 = B + (col0 + (c0 >> 2)) * (long)ldb + (c0 & 3) * 8;
  const u16* Bg1 = B + (col0 + (c1 >> 2)) * (long)ldb + (c1 & 3) * 8;
  u16* Al0 = &As[c0 * 8]; u16* Al1 = &As[c1 * 8];
  u16* Bl0 = &Bs[c0 * 8]; u16* Bl1 = &Bs[c1 * 8];

  for (int kk = 0; kk < K; kk += 32){
    __syncthreads();
    gload16(Ag0 + kk, Al0);
    gload16(Ag1 + kk, Al1);
    gload16(Bg0 + kk, Bl0);
    gload16(Bg1 + kk, Bl1);
    __syncthreads();
    short8 af[4], bfr[4];
#pragma unroll
    for (int mi = 0; mi < 4; mi++) af[mi]  = *(const short8*)&As[(wr*64 + mi*16 + l16)*32 + kq*8];
#pragma unroll
    for (int ni = 0; ni < 4; ni++) bfr[ni] = *(const short8*)&Bs[(wc*64 + ni*16 + l16)*32 + kq*8];
#pragma unroll
    for (int mi = 0; mi < 4; mi++)
#pragma unroll
      for (int ni = 0; ni < 4; ni++)
        acc[mi][ni] = __builtin_amdgcn_mfma_f32_16x16x32_bf16(af[mi], bfr[ni], acc[mi][ni], 0, 0, 0);
  }

#pragma unroll
  for (int mi = 0; mi < 4; mi++){
#pragma unroll
    for (int ni = 0; ni < 4; ni++){
#pragma unroll
      for (int qq = 0; qq < 4; qq++){
        const long r = row0 + wr*64 + mi*16 + kq*4 + qq;   // C/D: row=(lane>>4)*4+reg
        const long c = col0 + wc*64 + ni*16 + l16;          //      col=lane&15
        const float v = acc[mi][ni][qq];
        if (EPI == 0){
          ((u16*)Cv)[r * ldc + c] = f2b(v);
        } else if (EPI == 1){
          ((u16*)Cv)[r * ldc + c] = f2b(tanhf(v));
        } else if (EPI == 2){
          const float tm = e_vec[c];
          const float xc = e_x[r * ldc + c];
          const float xp = ((r & 2047) != 0) ? e_x[(r - 1) * ldc + c] : 0.0f;
          ((u16*)Cv)[r * ldc + c] = f2b(xc + (xp - xc) * (tm + v));
        } else if (EPI == 3){
          const float w = v + e_vec[c];
          ((float*)Cv)[r * ldc + c] = expf(-expf(w));
        } else if (EPI == 4){
          ((u16*)Cv)[r * ldc + c] = f2b(v / (1.0f + expf(-v)));
        } else {
          ((float*)Cv)[r * ldc + c] = v;
        }
      }
    }
  }
}

// ---------------------------------------------------------------------------
// XM = bf16(x + (x_prev - x) * time_maa_x)   (f32 in, 4 elems/thread)
// ---------------------------------------------------------------------------
__global__ __launch_bounds__(256) void mkxm_k(const float* __restrict__ X,
    const float* __restrict__ tmx, u16* __restrict__ XM)
{
  const long idx = (long)blockIdx.x * 256 + threadIdx.x;   // 4-elem chunk id
  const long m = idx >> 8;
  const int c4 = (int)(idx & 255) * 4;
  const float4 x = *(const float4*)(X + m * 1024 + c4);
  float4 p = make_float4(0.f, 0.f, 0.f, 0.f);
  if ((m & 2047) != 0) p = *(const float4*)(X + (m - 1) * 1024 + c4);
  const float4 t = *(const float4*)(tmx + c4);
  ushort4 o;
  o.x = f2b(x.x + (p.x - x.x) * t.x);
  o.y = f2b(x.y + (p.y - x.y) * t.y);
  o.z = f2b(x.z + (p.z - x.z) * t.z);
  o.w = f2b(x.w + (p.w - x.w) * t.w);
  *(ushort4*)(XM + m * 1024 + c4) = o;
}

// ---------------------------------------------------------------------------
// f32 -> bf16 cast, 4 elems/thread
// ---------------------------------------------------------------------------
__global__ __launch_bounds__(256) void cast_k(const float* __restrict__ src,
    u16* __restrict__ dst, long n4)
{
  const long i = (long)blockIdx.x * 256 + threadIdx.x;
  if (i >= n4) return;
  const float4 v = ((const float4*)src)[i];
  ushort4 o; o.x = f2b(v.x); o.y = f2b(v.y); o.z = f2b(v.z); o.w = f2b(v.w);
  ((ushort4*)dst)[i] = o;
}

// ---------------------------------------------------------------------------
// dst[n][k] = bf16( (n < Ccols) ? src[k][n] : 0 )   dst [dstR][R], idx = n*R+k
// ---------------------------------------------------------------------------
__global__ __launch_bounds__(256) void tpad_k(const float* __restrict__ src,
    u16* __restrict__ dst, int R, int Ccols, long total)
{
  const long idx = (long)blockIdx.x * 256 + threadIdx.x;
  if (idx >= total) return;
  const int k = (int)(idx % R);
  const int n = (int)(idx / R);
  dst[idx] = (n < Ccols) ? f2b(src[(long)k * Ccols + n]) : (u16)0;
}

// ---------------------------------------------------------------------------
// WKV6 chunked scan.  One block per (b,h); 32 chunks of L=64; S[64k][64j] LDS.
//  rt~_i = r_i * P_{i-1};  kt~_s = k_s / P_s;  M[i][s] = rt~_i . kt~_s (s<i)
//  y_i = rt~_i.S + sum_s M[i][s] v_s + (r_i.(u*k_i)) v_i
//  S <- P_63 * (S + sum_s kt~_s (x) v_s)
// ---------------------------------------------------------------------------
__global__ __launch_bounds__(256) void wkv_scan_k(
    const u16* __restrict__ Rg, const u16* __restrict__ Kg, const u16* __restrict__ Vg,
    const float* __restrict__ Dg, const float* __restrict__ Ug, float* __restrict__ Yg)
{
  __shared__ float S_[64 * 64];    // [k][j] stride 64
  __shared__ float KT_[64 * 68];   // [s][k] stride 68 (padded, 16B-aligned rows)
  __shared__ u16  RT_[64 * 66];    // [i][k] stride 66 (bf16)
  __shared__ u16  V_[64 * 66];     // [s][j] stride 66 (bf16)
  __shared__ u16  M_[64 * 66];     // [i][s] stride 66 (bf16)
  __shared__ float us_[64];
  __shared__ float ps_[64];
  __shared__ float dg_[64 * 4];

  const int tid = threadIdx.x;
  const int b = blockIdx.x >> 4;
  const int h = blockIdx.x & 15;
  const int cb = h * 64;

  if (tid < 64) us_[tid] = Ug[cb + tid];
  {
    const int e0 = tid * 16;
#pragma unroll
    for (int e = 0; e < 16; e++) S_[e0 + e] = 0.0f;
  }
  __syncthreads();

  const int iS = tid >> 2, sg = tid & 3;   // staging map: row iS, 16-elem segment sg
  const int i_ = tid & 63, q = tid >> 6;   // compute map: row i_, j/s-quarter q

  for (int ch = 0; ch < 32; ch++){
    const long rowb = (long)b * 2048 + ch * 64;
    // ---- P0: stage r,k,v
    {
      const long go = (rowb + iS) * 1024 + cb + sg * 16;
      const uint4 ra = *(const uint4*)(Rg + go);
      const uint4 rb = *(const uint4*)(Rg + go + 8);
      u32* rd = (u32*)&RT_[iS * 66 + sg * 16];
      rd[0] = ra.x; rd[1] = ra.y; rd[2] = ra.z; rd[3] = ra.w;
      rd[4] = rb.x; rd[5] = rb.y; rd[6] = rb.z; rd[7] = rb.w;
      const uint4 ka = *(const uint4*)(Kg + go);
      const uint4 kb = *(const uint4*)(Kg + go + 8);
      float* kd = &KT_[iS * 68 + sg * 16];
      const u32 kw[8] = {ka.x, ka.y, ka.z, ka.w, kb.x, kb.y, kb.z, kb.w};
#pragma unroll
      for (int e = 0; e < 8; e++){ kd[2*e] = b2f(LOH(kw[e])); kd[2*e+1] = b2f(HIH(kw[e])); }
      const uint4 va = *(const uint4*)(Vg + go);
      const uint4 vb = *(const uint4*)(Vg + go + 8);
      u32* vd = (u32*)&V_[iS * 66 + sg * 16];
      vd[0] = va.x; vd[1] = va.y; vd[2] = va.z; vd[3] = va.w;
      vd[4] = vb.x; vd[5] = vb.y; vd[6] = vb.z; vd[7] = vb.w;
    }
    __syncthreads();
    // ---- P0b: diag partial with RAW r,k:  sum_k r*u*k over this quarter
    {
      float ds = 0.0f;
#pragma unroll
      for (int kk = 0; kk < 16; kk++){
        const int k = q * 16 + kk;
        ds += b2f(RT_[i_ * 66 + k]) * us_[k] * KT_[i_ * 68 + k];
      }
      dg_[i_ * 4 + q] = ds;
    }
    __syncthreads();
    // ---- P0c: cumulative decay products; convert RT->rt~, KT->kt~ in place
    if (tid < 64){
      const int k = tid;
      float p = 1.0f;
      for (int i = 0; i < 64; i++){
        const float d = Dg[(rowb + i) * 1024 + cb + k];
        RT_[i * 66 + k] = f2b(b2f(RT_[i * 66 + k]) * p);   // * P_{i-1}
        p *= d;
        KT_[i * 68 + k] *= (1.0f / p);                     // / P_i
      }
      ps_[k] = p;
    }
    __syncthreads();
    // ---- P2: load rt row into regs; scores M[i][s] for this quarter's s
    float rt[64];
    {
      const u32* rr = (const u32*)&RT_[i_ * 66];
#pragma unroll
      for (int kk = 0; kk < 32; kk++){
        const u32 u = rr[kk];
        rt[2*kk] = b2f(LOH(u)); rt[2*kk+1] = b2f(HIH(u));
      }
    }
    for (int ss = 0; ss < 16; ss++){
      const int s = q * 16 + ss;
      const float4* kr = (const float4*)&KT_[s * 68];      // broadcast row read
      float m = 0.0f;
#pragma unroll
      for (int k4 = 0; k4 < 16; k4++){
        const float4 kv = kr[k4];
        m += rt[4*k4+0]*kv.x + rt[4*k4+1]*kv.y + rt[4*k4+2]*kv.z + rt[4*k4+3]*kv.w;
      }
      M_[i_ * 66 + s] = f2b(s < i_ ? m : 0.0f);
    }
    __syncthreads();
    // ---- P3: y_i for this thread's 16 j's
    {
      float y[16];
      const float dgi = dg_[i_*4+0] + dg_[i_*4+1] + dg_[i_*4+2] + dg_[i_*4+3];
      const int jb = q * 16;
      {
        const u32* vr = (const u32*)&V_[i_ * 66 + jb];
#pragma unroll
        for (int j2 = 0; j2 < 8; j2++){
          const u32 u = vr[j2];
          y[2*j2] = dgi * b2f(LOH(u)); y[2*j2+1] = dgi * b2f(HIH(u));
        }
      }
#pragma unroll
      for (int k = 0; k < 64; k++){
        const float rk = rt[k];
        const float4* sr = (const float4*)&S_[k * 64 + jb];  // broadcast row read
#pragma unroll
        for (int j4 = 0; j4 < 4; j4++){
          const float4 sv = sr[j4];
          y[4*j4+0] += rk*sv.x; y[4*j4+1] += rk*sv.y; y[4*j4+2] += rk*sv.z; y[4*j4+3] += rk*sv.w;
        }
      }
      for (int s = 0; s < 64; s++){
        const float mf = b2f(M_[i_ * 66 + s]);               // zero for s>=i
        const u32* vr = (const u32*)&V_[s * 66 + jb];
#pragma unroll
        for (int j2 = 0; j2 < 8; j2++){
          const u32 u = vr[j2];
          y[2*j2]   += mf * b2f(LOH(u));
          y[2*j2+1] += mf * b2f(HIH(u));
        }
      }
      float* yo = Yg + (rowb + i_) * 1024 + cb + jb;
#pragma unroll
      for (int j4 = 0; j4 < 4; j4++)
        *(float4*)(yo + 4*j4) = make_float4(y[4*j4], y[4*j4+1], y[4*j4+2], y[4*j4+3]);
    }
    __syncthreads();
    // ---- P4: S <- ps * (S + kt~^T V)   thread: column j, k-quarter qq
    {
      const int j = tid & 63, qq = tid >> 6;
      float sa[16];
#pragma unroll
      for (int kk = 0; kk < 16; kk++) sa[kk] = S_[(qq*16 + kk) * 64 + j];
      for (int s = 0; s < 64; s++){
        const float vf = b2f(V_[s * 66 + j]);
        const float* krow = &KT_[s * 68 + qq * 16];          // broadcast reads
#pragma unroll
        for (int kk = 0; kk < 16; kk++) sa[kk] += krow[kk] * vf;
      }
#pragma unroll
      for (int kk = 0; kk < 16; kk++){
        const int k = qq * 16 + kk;
        S_[k * 64 + j] = sa[kk] * ps_[k];
      }
    }
    __syncthreads();
  }
}

// ---------------------------------------------------------------------------
// GroupNorm over each head's 64 channels, then * g   (one block per bt row)
// ---------------------------------------------------------------------------
__global__ __launch_bounds__(256) void gnorm_k(const float* __restrict__ Y,
    const u16* __restrict__ G, const float* __restrict__ lng,
    const float* __restrict__ lnb, u16* __restrict__ Z)
{
  const long row = blockIdx.x;
  const int tid = threadIdx.x;
  const int hh = tid >> 4, l = tid & 15;
  const int c = hh * 64 + l * 4;
  const float4 v = *(const float4*)(Y + row * 1024 + c);
  float s = v.x + v.y + v.z + v.w;
  float sq = v.x*v.x + v.y*v.y + v.z*v.z + v.w*v.w;
#pragma unroll
  for (int off = 1; off < 16; off <<= 1){ s += __shfl_xor(s, off); sq += __shfl_xor(sq, off); }
  const float mean = s * 0.015625f;
  const float var = sq * 0.015625f - mean * mean;
  const float rstd = rsqrtf(var + 6.4e-4f);   // eps = 1e-5 * 64
  const uint2 gg = *(const uint2*)(G + row * 1024 + c);
  const float4 lg = *(const float4*)(lng + c);
  const float4 lb = *(const float4*)(lnb + c);
  const float vv[4] = {v.x, v.y, v.z, v.w};
  const float lgs[4] = {lg.x, lg.y, lg.z, lg.w};
  const float lbs[4] = {lb.x, lb.y, lb.z, lb.w};
  const u32 gs[2] = {gg.x, gg.y};
  ushort4 o;
  u16* op = (u16*)&o;
#pragma unroll
  for (int e = 0; e < 4; e++){
    const float gv = b2f((e & 1) ? HIH(gs[e >> 1]) : LOH(gs[e >> 1]));
    op[e] = f2b(((vv[e] - mean) * rstd * lgs[e] + lbs[e]) * gv);
  }
  *(ushort4*)(Z + row * 1024 + c) = o;
}

// ---------------------------------------------------------------------------
extern "C" void kernel_launch(void* const* d_in, const int* in_sizes, int n_in,
                              void* d_out, int out_size, void* d_ws, size_t ws_size,
                              hipStream_t stream)
{
  (void)in_sizes; (void)n_in; (void)out_size; (void)ws_size;
  const float* X    = (const float*)d_in[0];
  const float* TMX  = (const float*)d_in[1];
  const float* TMW  = (const float*)d_in[2];
  const float* TMK  = (const float*)d_in[3];
  const float* TMV  = (const float*)d_in[4];
  const float* TMR  = (const float*)d_in[5];
  const float* TMG  = (const float*)d_in[6];
  const float* MW1  = (const float*)d_in[7];
  const float* MW2  = (const float*)d_in[8];
  const float* TD   = (const float*)d_in[9];
  const float* TDW1 = (const float*)d_in[10];
  const float* TDW2 = (const float*)d_in[11];
  const float* U    = (const float*)d_in[12];
  const float* WR   = (const float*)d_in[13];
  const float* WK   = (const float*)d_in[14];
  const float* WV   = (const float*)d_in[15];
  const float* WG   = (const float*)d_in[16];
  const float* WO   = (const float*)d_in[17];
  const float* LNG  = (const float*)d_in[18];
  const float* LNB  = (const float*)d_in[19];

  char* ws = (char*)d_ws;
  const size_t SLOT = 16777216ULL;     // B*T*C bf16 bytes
  u16* S1 = (u16*)(ws + 0 * SLOT);     // XM  -> Rb
  u16* S2 = (u16*)(ws + 1 * SLOT);     // XW  -> Y lo
  u16* S3 = (u16*)(ws + 2 * SLOT);     // XK  -> Y hi
  u16* S4 = (u16*)(ws + 3 * SLOT);     // XV  -> Z
  u16* S5 = (u16*)(ws + 4 * SLOT);     // XR  -> DEC lo
  u16* S6 = (u16*)(ws + 5 * SLOT);     // XG  -> DEC hi
  u16* S7 = (u16*)(ws + 6 * SLOT);     // Kb
  u16* S8 = (u16*)(ws + 7 * SLOT);     // Vb
  u16* S9 = (u16*)(ws + 8 * SLOT);     // Gb
  char* p = ws + 9 * SLOT;
  auto alloc = [&](size_t bytes) -> void* {
    void* q = p; p += (bytes + 255) & ~(size_t)255; return q;
  };
  u16* MIXB = (u16*)alloc(8192ULL * 256 * 2);
  u16* Hb   = (u16*)alloc(8192ULL * 128 * 2);
  u16* W1T  = (u16*)alloc(256ULL * 1024 * 2);
  u16* W2T  = (u16*)alloc(5ULL * 1024 * 32 * 2);
  u16* TW1T = (u16*)alloc(128ULL * 1024 * 2);
  u16* TW2T = (u16*)alloc(1024ULL * 64 * 2);
  u16* WRb  = (u16*)alloc(1048576ULL * 2);
  u16* WKb  = (u16*)alloc(1048576ULL * 2);
  u16* WVb  = (u16*)alloc(1048576ULL * 2);
  u16* WGb  = (u16*)alloc(1048576ULL * 2);
  u16* WOb  = (u16*)alloc(1048576ULL * 2);

  u16*   XM = S1; u16* XW = S2; u16* XK = S3; u16* XV = S4; u16* XR = S5; u16* XG = S6;
  u16*   Rb = S1; u16* Kb = S7; u16* Vb = S8; u16* Gb = S9;
  float* Y   = (float*)S2;    // spans S2+S3 (xw,xk dead)
  float* DEC = (float*)S5;    // spans S5+S6 (xr,xg dead)
  u16*   Z   = S4;            // xv dead

  // weight casts / transposes (f32 -> bf16, [N][K] K-contiguous)
  cast_k<<<1024, 256, 0, stream>>>(WR, WRb, 262144);
  cast_k<<<1024, 256, 0, stream>>>(WK, WKb, 262144);
  cast_k<<<1024, 256, 0, stream>>>(WV, WVb, 262144);
  cast_k<<<1024, 256, 0, stream>>>(WG, WGb, 262144);
  cast_k<<<1024, 256, 0, stream>>>(WO, WOb, 262144);
  tpad_k<<<1024, 256, 0, stream>>>(MW1, W1T, 1024, 160, 256LL * 1024);
  for (int f = 0; f < 5; f++)
    tpad_k<<<128, 256, 0, stream>>>(MW2 + f * 32768, W2T + f * 32768, 32, 1024, 1024LL * 32);
  tpad_k<<<512, 256, 0, stream>>>(TDW1, TW1T, 1024, 64, 128LL * 1024);
  tpad_k<<<256, 256, 0, stream>>>(TDW2, TW2T, 64, 1024, 1024LL * 64);

  // XM = x + xx*time_maa_x
  mkxm_k<<<8192, 256, 0, stream>>>(X, TMX, XM);

  // mix160 = tanh(XM @ maa_w1)        [8192,256(pad)]
  gemm_bt<1><<<dim3(64, 2), 256, 0, stream>>>(XM, 1024, W1T, 1024, MIXB, 256, 1024, nullptr, nullptr);

  // x{w,k,v,r,g} = x + xx*(tm + mix_f @ maa_w2_f)
  gemm_bt<2><<<dim3(64, 8), 256, 0, stream>>>(MIXB + 0,   256, W2T + 0*32768, 32, XW, 1024, 32, X, TMW);
  gemm_bt<2><<<dim3(64, 8), 256, 0, stream>>>(MIXB + 32,  256, W2T + 1*32768, 32, XK, 1024, 32, X, TMK);
  gemm_bt<2><<<dim3(64, 8), 256, 0, stream>>>(MIXB + 64,  256, W2T + 2*32768, 32, XV, 1024, 32, X, TMV);
  gemm_bt<2><<<dim3(64, 8), 256, 0, stream>>>(MIXB + 96,  256, W2T + 3*32768, 32, XR, 1024, 32, X, TMR);
  gemm_bt<2><<<dim3(64, 8), 256, 0, stream>>>(MIXB + 128, 256, W2T + 4*32768, 32, XG, 1024, 32, X, TMG);

  // r, k, v, g   (Rb overwrites XM slot — XM dead after MIXB gemm)
  gemm_bt<0><<<dim3(64, 8), 256, 0, stream>>>(XR, 1024, WRb, 1024, Rb, 1024, 1024, nullptr, nullptr);
  gemm_bt<0><<<dim3(64, 8), 256, 0, stream>>>(XK, 1024, WKb, 1024, Kb, 1024, 1024, nullptr, nullptr);
  gemm_bt<0><<<dim3(64, 8), 256, 0, stream>>>(XV, 1024, WVb, 1024, Vb, 1024, 1024, nullptr, nullptr);
  gemm_bt<4><<<dim3(64, 8), 256, 0, stream>>>(XG, 1024, WGb, 1024, Gb, 1024, 1024, nullptr, nullptr);

  // h = tanh(xw @ td_w1);  decay = exp(-exp(time_decay + h @ td_w2))
  gemm_bt<1><<<dim3(64, 1), 256, 0, stream>>>(XW, 1024, TW1T, 1024, Hb, 128, 1024, nullptr, nullptr);
  gemm_bt<3><<<dim3(64, 8), 256, 0, stream>>>(Hb, 128, TW2T, 64, DEC, 1024, 64, nullptr, TD);

  // WKV6 chunked scan -> y (f32, spans S2+S3)
  wkv_scan_k<<<64, 256, 0, stream>>>(Rb, Kb, Vb, DEC, U, Y);

  // GroupNorm(y)*g -> z
  gnorm_k<<<8192, 256, 0, stream>>>(Y, Gb, LNG, LNB, Z);

  // out = z @ Wo^T   (f32 out)
  gemm_bt<5><<<dim3(64, 8), 256, 0, stream>>>(Z, 1024, WOb, 1024, (float*)d_out, 1024, 1024, nullptr, nullptr);
}

// Round 3
// 482.896 us; speedup vs baseline: 2.5949x; 2.5949x over previous
//
#include <hip/hip_runtime.h>

typedef unsigned int u32;
typedef unsigned short u16;
typedef __attribute__((ext_vector_type(8))) short short8;
typedef __attribute__((ext_vector_type(4))) float f32x4;

__device__ __forceinline__ float b2f(u16 h){ u32 x = ((u32)h) << 16; return __builtin_bit_cast(float, x); }
__device__ __forceinline__ u16 f2b(float f){
  u32 x = __builtin_bit_cast(u32, f);
  x += 0x7fffu + ((x >> 16) & 1u);
  return (u16)(x >> 16);
}
#define LOH(u) ((u16)((u) & 0xffffu))
#define HIH(u) ((u16)((u) >> 16))

__device__ __forceinline__ void gload16(const u16* g, u16* lds){
  __builtin_amdgcn_global_load_lds((const __attribute__((address_space(1))) u32*)g,
                                   (__attribute__((address_space(3))) u32*)lds, 16, 0, 0);
}

// ---------------------------------------------------------------------------
// Generic MFMA GEMM: C[M,N] = A[M,K] * B[N,K]^T   (A,B bf16 K-contiguous)
// 128x128 tile, BK=32, 256 threads (4 waves 2x2), 16x16x32 bf16 MFMA.
// EPI: 0 bf16, 1 tanh bf16, 2 token-mix bf16 (e_x,e_vec f32), 3 decay f32,
//      4 silu bf16, 5 plain f32
// ---------------------------------------------------------------------------
template<int EPI>
__global__ __launch_bounds__(256) void gemm_bt(
    const u16* __restrict__ A, int lda,
    const u16* __restrict__ B, int ldb,
    void* __restrict__ Cv, int ldc, int K,
    const float* __restrict__ e_x, const float* __restrict__ e_vec)
{
  __shared__ u16 As[4096];
  __shared__ u16 Bs[4096];
  const int tid = threadIdx.x;
  const int wave = tid >> 6, lane = tid & 63;
  const int wr = wave >> 1, wc = wave & 1;
  const int l16 = lane & 15, kq = lane >> 4;
  const long row0 = (long)blockIdx.x * 128;
  const long col0 = (long)blockIdx.y * 128;

  f32x4 acc[4][4];
#pragma unroll
  for (int i = 0; i < 4; i++)
#pragma unroll
    for (int j = 0; j < 4; j++) acc[i][j] = (f32x4)0.0f;

  const int c0 = tid, c1 = tid + 256;
  const u16* Ag0 = A + (row0 + (c0 >> 2)) * (long)lda + (c0 & 3) * 8;
  const u16* Ag1 = A + (row0 + (c1 >> 2)) * (long)lda + (c1 & 3) * 8;
  const u16* Bg0 = B + (col0 + (c0 >> 2)) * (long)ldb + (c0 & 3) * 8;
  const u16* Bg1 = B + (col0 + (c1 >> 2)) * (long)ldb + (c1 & 3) * 8;
  u16* Al0 = &As[c0 * 8]; u16* Al1 = &As[c1 * 8];
  u16* Bl0 = &Bs[c0 * 8]; u16* Bl1 = &Bs[c1 * 8];

  for (int kk = 0; kk < K; kk += 32){
    __syncthreads();
    gload16(Ag0 + kk, Al0);
    gload16(Ag1 + kk, Al1);
    gload16(Bg0 + kk, Bl0);
    gload16(Bg1 + kk, Bl1);
    __syncthreads();
    short8 af[4], bfr[4];
#pragma unroll
    for (int mi = 0; mi < 4; mi++) af[mi]  = *(const short8*)&As[(wr*64 + mi*16 + l16)*32 + kq*8];
#pragma unroll
    for (int ni = 0; ni < 4; ni++) bfr[ni] = *(const short8*)&Bs[(wc*64 + ni*16 + l16)*32 + kq*8];
#pragma unroll
    for (int mi = 0; mi < 4; mi++)
#pragma unroll
      for (int ni = 0; ni < 4; ni++)
        acc[mi][ni] = __builtin_amdgcn_mfma_f32_16x16x32_bf16(af[mi], bfr[ni], acc[mi][ni], 0, 0, 0);
  }

#pragma unroll
  for (int mi = 0; mi < 4; mi++){
#pragma unroll
    for (int ni = 0; ni < 4; ni++){
#pragma unroll
      for (int qq = 0; qq < 4; qq++){
        const long r = row0 + wr*64 + mi*16 + kq*4 + qq;   // C/D: row=(lane>>4)*4+reg
        const long c = col0 + wc*64 + ni*16 + l16;          //      col=lane&15
        const float v = acc[mi][ni][qq];
        if (EPI == 0){
          ((u16*)Cv)[r * ldc + c] = f2b(v);
        } else if (EPI == 1){
          ((u16*)Cv)[r * ldc + c] = f2b(tanhf(v));
        } else if (EPI == 2){
          const float tm = e_vec[c];
          const float xc = e_x[r * ldc + c];
          const float xp = ((r & 2047) != 0) ? e_x[(r - 1) * ldc + c] : 0.0f;
          ((u16*)Cv)[r * ldc + c] = f2b(xc + (xp - xc) * (tm + v));
        } else if (EPI == 3){
          const float w = v + e_vec[c];
          ((float*)Cv)[r * ldc + c] = expf(-expf(w));
        } else if (EPI == 4){
          ((u16*)Cv)[r * ldc + c] = f2b(v / (1.0f + expf(-v)));
        } else {
          ((float*)Cv)[r * ldc + c] = v;
        }
      }
    }
  }
}

// ---------------------------------------------------------------------------
// XM = bf16(x + (x_prev - x) * time_maa_x)   (f32 in, 4 elems/thread)
// ---------------------------------------------------------------------------
__global__ __launch_bounds__(256) void mkxm_k(const float* __restrict__ X,
    const float* __restrict__ tmx, u16* __restrict__ XM)
{
  const long idx = (long)blockIdx.x * 256 + threadIdx.x;   // 4-elem chunk id
  const long m = idx >> 8;
  const int c4 = (int)(idx & 255) * 4;
  const float4 x = *(const float4*)(X + m * 1024 + c4);
  float4 p = make_float4(0.f, 0.f, 0.f, 0.f);
  if ((m & 2047) != 0) p = *(const float4*)(X + (m - 1) * 1024 + c4);
  const float4 t = *(const float4*)(tmx + c4);
  ushort4 o;
  o.x = f2b(x.x + (p.x - x.x) * t.x);
  o.y = f2b(x.y + (p.y - x.y) * t.y);
  o.z = f2b(x.z + (p.z - x.z) * t.z);
  o.w = f2b(x.w + (p.w - x.w) * t.w);
  *(ushort4*)(XM + m * 1024 + c4) = o;
}

// ---------------------------------------------------------------------------
// f32 -> bf16 cast, 4 elems/thread
// ---------------------------------------------------------------------------
__global__ __launch_bounds__(256) void cast_k(const float* __restrict__ src,
    u16* __restrict__ dst, long n4)
{
  const long i = (long)blockIdx.x * 256 + threadIdx.x;
  if (i >= n4) return;
  const float4 v = ((const float4*)src)[i];
  ushort4 o; o.x = f2b(v.x); o.y = f2b(v.y); o.z = f2b(v.z); o.w = f2b(v.w);
  ((ushort4*)dst)[i] = o;
}

// ---------------------------------------------------------------------------
// dst[n][k] = bf16( (n < Ccols) ? src[k][n] : 0 )   dst [dstR][R], idx = n*R+k
// ---------------------------------------------------------------------------
__global__ __launch_bounds__(256) void tpad_k(const float* __restrict__ src,
    u16* __restrict__ dst, int R, int Ccols, long total)
{
  const long idx = (long)blockIdx.x * 256 + threadIdx.x;
  if (idx >= total) return;
  const int k = (int)(idx % R);
  const int n = (int)(idx / R);
  dst[idx] = (n < Ccols) ? f2b(src[(long)k * Ccols + n]) : (u16)0;
}

// ---------------------------------------------------------------------------
// WKV6 stage 1 — per-(b,h,chunk) intra-chunk work. One block per chunk.
//  writes: Yg = M.V + diag.v (partial), Ag = kt~^T V, Pg = chunk decay prod,
//          Rg <- rt~ = r * P_{i-1}  (in place, bf16)
// ---------------------------------------------------------------------------
__global__ __launch_bounds__(256) void wkv_s1(
    u16* __restrict__ Rg, const u16* __restrict__ Kg, const u16* __restrict__ Vg,
    const float* __restrict__ Dg, const float* __restrict__ Ug,
    float* __restrict__ Yg, float* __restrict__ Ag, float* __restrict__ Pg)
{
  __shared__ float KT_[64 * 68];     // raw k -> kt~ (f32), stride 68
  __shared__ u16  RT_[64 * 66];      // raw r -> rt~ (bf16), stride 66
  __shared__ u16  V_[64 * 66];       // v (bf16), stride 66
  __shared__ char DM_[64 * 68 * 4];  // union: D tile (f32 s68) then M (u16 s66)
  __shared__ float us_[64];
  __shared__ float dg_[64 * 4];
  float* D_ = (float*)DM_;
  u16*  M_  = (u16*)DM_;

  const int tid = threadIdx.x;
  const int bh = blockIdx.x >> 5;      // 0..63
  const int ch = blockIdx.x & 31;      // 0..31
  const int b = bh >> 4, h = bh & 15;
  const int cb = h * 64;
  const long rowb = (long)b * 2048 + ch * 64;

  if (tid < 64) us_[tid] = Ug[cb + tid];

  const int iS = tid >> 2, sg = tid & 3;   // staging map
  const int i_ = tid & 63, q = tid >> 6;   // compute map

  // ---- P0: stage r,k,v,d
  {
    const long go = (rowb + iS) * 1024 + cb + sg * 16;
    const uint4 ra = *(const uint4*)(Rg + go);
    const uint4 rb = *(const uint4*)(Rg + go + 8);
    u32* rd = (u32*)&RT_[iS * 66 + sg * 16];
    rd[0] = ra.x; rd[1] = ra.y; rd[2] = ra.z; rd[3] = ra.w;
    rd[4] = rb.x; rd[5] = rb.y; rd[6] = rb.z; rd[7] = rb.w;
    const uint4 ka = *(const uint4*)(Kg + go);
    const uint4 kb = *(const uint4*)(Kg + go + 8);
    float* kd = &KT_[iS * 68 + sg * 16];
    const u32 kw[8] = {ka.x, ka.y, ka.z, ka.w, kb.x, kb.y, kb.z, kb.w};
#pragma unroll
    for (int e = 0; e < 8; e++){ kd[2*e] = b2f(LOH(kw[e])); kd[2*e+1] = b2f(HIH(kw[e])); }
    const uint4 va = *(const uint4*)(Vg + go);
    const uint4 vb = *(const uint4*)(Vg + go + 8);
    u32* vd = (u32*)&V_[iS * 66 + sg * 16];
    vd[0] = va.x; vd[1] = va.y; vd[2] = va.z; vd[3] = va.w;
    vd[4] = vb.x; vd[5] = vb.y; vd[6] = vb.z; vd[7] = vb.w;
    float4* dd = (float4*)&D_[iS * 68 + sg * 16];
    const float4* dsrc = (const float4*)(Dg + go);
    dd[0] = dsrc[0]; dd[1] = dsrc[1]; dd[2] = dsrc[2]; dd[3] = dsrc[3];
  }
  __syncthreads();
  // ---- P0b: diag partial with RAW r,k
  {
    float ds = 0.0f;
#pragma unroll
    for (int kk = 0; kk < 16; kk++){
      const int k = q * 16 + kk;
      ds += b2f(RT_[i_ * 66 + k]) * us_[k] * KT_[i_ * 68 + k];
    }
    dg_[i_ * 4 + q] = ds;
  }
  __syncthreads();
  // ---- P0c: prefix decay per channel; RT->rt~, KT->kt~ in place; Pg out
  if (tid < 64){
    const int k = tid;
    float p = 1.0f;
#pragma unroll
    for (int i = 0; i < 64; i++){
      const float d = D_[i * 68 + k];
      RT_[i * 66 + k] = f2b(b2f(RT_[i * 66 + k]) * p);   // * P_{i-1}
      p *= d;
      KT_[i * 68 + k] *= (1.0f / p);                     // / P_i
    }
    Pg[((long)bh * 32 + ch) * 64 + k] = p;
  }
  __syncthreads();
  // ---- writeback rt~ to Rg (in place) + P2 scores
  {
    const u32* rr = (const u32*)&RT_[i_ * 66 + q * 16];
    u32* out = (u32*)(Rg + (rowb + i_) * 1024 + cb + q * 16);
#pragma unroll
    for (int e = 0; e < 8; e++) out[e] = rr[e];
  }
  float rt[64];
  {
    const u32* rr = (const u32*)&RT_[i_ * 66];
#pragma unroll
    for (int kk = 0; kk < 32; kk++){
      const u32 u = rr[kk];
      rt[2*kk] = b2f(LOH(u)); rt[2*kk+1] = b2f(HIH(u));
    }
  }
  for (int ss = 0; ss < 16; ss++){
    const int s = q * 16 + ss;
    const float4* kr = (const float4*)&KT_[s * 68];        // broadcast row
    float m = 0.0f;
#pragma unroll
    for (int k4 = 0; k4 < 16; k4++){
      const float4 kv = kr[k4];
      m += rt[4*k4+0]*kv.x + rt[4*k4+1]*kv.y + rt[4*k4+2]*kv.z + rt[4*k4+3]*kv.w;
    }
    M_[i_ * 66 + s] = f2b(s < i_ ? m : 0.0f);
  }
  __syncthreads();
  // ---- P3: ypart_i = dgi*v_i + sum_s M[i][s] v_s
  {
    float y[16];
    const float dgi = dg_[i_*4+0] + dg_[i_*4+1] + dg_[i_*4+2] + dg_[i_*4+3];
    const int jb = q * 16;
    {
      const u32* vr = (const u32*)&V_[i_ * 66 + jb];
#pragma unroll
      for (int j2 = 0; j2 < 8; j2++){
        const u32 u = vr[j2];
        y[2*j2] = dgi * b2f(LOH(u)); y[2*j2+1] = dgi * b2f(HIH(u));
      }
    }
    for (int s = 0; s < 64; s++){
      const float mf = b2f(M_[i_ * 66 + s]);               // zero for s>=i
      const u32* vr = (const u32*)&V_[s * 66 + jb];
#pragma unroll
      for (int j2 = 0; j2 < 8; j2++){
        const u32 u = vr[j2];
        y[2*j2]   += mf * b2f(LOH(u));
        y[2*j2+1] += mf * b2f(HIH(u));
      }
    }
    float* yo = Yg + (rowb + i_) * 1024 + cb + jb;
#pragma unroll
    for (int j4 = 0; j4 < 4; j4++)
      *(float4*)(yo + 4*j4) = make_float4(y[4*j4], y[4*j4+1], y[4*j4+2], y[4*j4+3]);
  }
  // ---- P4: A[k][j] = sum_s kt~_s[k] v_s[j]   (thread: col j, k-quarter qq)
  {
    const int j = tid & 63, qq = tid >> 6;
    float sa[16];
#pragma unroll
    for (int kk = 0; kk < 16; kk++) sa[kk] = 0.0f;
    for (int s = 0; s < 64; s++){
      const float vf = b2f(V_[s * 66 + j]);
      const float* krow = &KT_[s * 68 + qq * 16];          // broadcast reads
#pragma unroll
      for (int kk = 0; kk < 16; kk++) sa[kk] += krow[kk] * vf;
    }
    float* aout = Ag + ((long)bh * 32 + ch) * 4096;
#pragma unroll
    for (int kk = 0; kk < 16; kk++)
      aout[(qq*16 + kk) * 64 + j] = sa[kk];
  }
}

// ---------------------------------------------------------------------------
// WKV6 stage 2 — inter-chunk recurrence S_{c+1} = ps_c*(S_c + A_c).
// Block = (bh, k-quarter); state float4/thread in regs; writes chunk-START S.
// ---------------------------------------------------------------------------
__global__ __launch_bounds__(256) void wkv_s2(
    const float* __restrict__ Ag, const float* __restrict__ Pg, float* __restrict__ Sg)
{
  const int tid = threadIdx.x;
  const int bh = blockIdx.x >> 2, kq = blockIdx.x & 3;
  const int kk = tid >> 4, jo = tid & 15;
  const int krow = kq * 16 + kk;
  const long base = (long)bh * 32;
  float4 S = make_float4(0.f, 0.f, 0.f, 0.f);
  for (int c = 0; c < 32; c++){
    const long mo = (base + c) * 4096 + krow * 64 + jo * 4;
    *(float4*)(Sg + mo) = S;
    const float4 a = *(const float4*)(Ag + mo);
    const float ps = Pg[(base + c) * 64 + krow];
    S.x = ps * (S.x + a.x); S.y = ps * (S.y + a.y);
    S.z = ps * (S.z + a.z); S.w = ps * (S.w + a.w);
  }
}

// ---------------------------------------------------------------------------
// WKV6 stage 3 — cross term: Yg += rt~ . S_chunkstart.  Block per (bh,chunk).
// ---------------------------------------------------------------------------
__global__ __launch_bounds__(256) void wkv_s3(
    const u16* __restrict__ Rtg, const float* __restrict__ Sg, float* __restrict__ Yg)
{
  __shared__ float Ss[4096];        // [k][j] stride 64 (broadcast-row reads)
  __shared__ u16 RTs[64 * 66];
  const int tid = threadIdx.x;
  const int bh = blockIdx.x >> 5, ch = blockIdx.x & 31;
  if (ch == 0) return;              // S_start = 0
  const int b = bh >> 4, h = bh & 15, cb = h * 64;
  const long rowb = (long)b * 2048 + ch * 64;

  {
    const float4* sp = (const float4*)(Sg + ((long)bh * 32 + ch) * 4096);
    float4* sd = (float4*)Ss;
#pragma unroll
    for (int e = 0; e < 4; e++) sd[tid + e * 256] = sp[tid + e * 256];
  }
  {
    const int iS = tid >> 2, sg4 = tid & 3;
    const u32* src = (const u32*)(Rtg + (rowb + iS) * 1024 + cb + sg4 * 16);
    u32* dst = (u32*)&RTs[iS * 66 + sg4 * 16];
#pragma unroll
    for (int e = 0; e < 8; e++) dst[e] = src[e];
  }
  __syncthreads();

  const int i_ = tid & 63, q = tid >> 6, jb = q * 16;
  float rt[64];
  {
    const u32* rr = (const u32*)&RTs[i_ * 66];
#pragma unroll
    for (int kk = 0; kk < 32; kk++){
      const u32 u = rr[kk];
      rt[2*kk] = b2f(LOH(u)); rt[2*kk+1] = b2f(HIH(u));
    }
  }
  float* yo = Yg + (rowb + i_) * 1024 + cb + jb;
  float y[16];
#pragma unroll
  for (int j4 = 0; j4 < 4; j4++){
    const float4 v = *(const float4*)(yo + 4*j4);
    y[4*j4] = v.x; y[4*j4+1] = v.y; y[4*j4+2] = v.z; y[4*j4+3] = v.w;
  }
#pragma unroll
  for (int k = 0; k < 64; k++){
    const float rk = rt[k];
    const float4* sr = (const float4*)&Ss[k * 64 + jb];    // broadcast row
#pragma unroll
    for (int j4 = 0; j4 < 4; j4++){
      const float4 sv = sr[j4];
      y[4*j4+0] += rk*sv.x; y[4*j4+1] += rk*sv.y; y[4*j4+2] += rk*sv.z; y[4*j4+3] += rk*sv.w;
    }
  }
#pragma unroll
  for (int j4 = 0; j4 < 4; j4++)
    *(float4*)(yo + 4*j4) = make_float4(y[4*j4], y[4*j4+1], y[4*j4+2], y[4*j4+3]);
}

// ---------------------------------------------------------------------------
// GroupNorm over each head's 64 channels, then * g   (one block per bt row)
// ---------------------------------------------------------------------------
__global__ __launch_bounds__(256) void gnorm_k(const float* __restrict__ Y,
    const u16* __restrict__ G, const float* __restrict__ lng,
    const float* __restrict__ lnb, u16* __restrict__ Z)
{
  const long row = blockIdx.x;
  const int tid = threadIdx.x;
  const int hh = tid >> 4, l = tid & 15;
  const int c = hh * 64 + l * 4;
  const float4 v = *(const float4*)(Y + row * 1024 + c);
  float s = v.x + v.y + v.z + v.w;
  float sq = v.x*v.x + v.y*v.y + v.z*v.z + v.w*v.w;
#pragma unroll
  for (int off = 1; off < 16; off <<= 1){ s += __shfl_xor(s, off); sq += __shfl_xor(sq, off); }
  const float mean = s * 0.015625f;
  const float var = sq * 0.015625f - mean * mean;
  const float rstd = rsqrtf(var + 6.4e-4f);   // eps = 1e-5 * 64
  const uint2 gg = *(const uint2*)(G + row * 1024 + c);
  const float4 lg = *(const float4*)(lng + c);
  const float4 lb = *(const float4*)(lnb + c);
  const float vv[4] = {v.x, v.y, v.z, v.w};
  const float lgs[4] = {lg.x, lg.y, lg.z, lg.w};
  const float lbs[4] = {lb.x, lb.y, lb.z, lb.w};
  const u32 gs[2] = {gg.x, gg.y};
  ushort4 o;
  u16* op = (u16*)&o;
#pragma unroll
  for (int e = 0; e < 4; e++){
    const float gv = b2f((e & 1) ? HIH(gs[e >> 1]) : LOH(gs[e >> 1]));
    op[e] = f2b(((vv[e] - mean) * rstd * lgs[e] + lbs[e]) * gv);
  }
  *(ushort4*)(Z + row * 1024 + c) = o;
}

// ---------------------------------------------------------------------------
extern "C" void kernel_launch(void* const* d_in, const int* in_sizes, int n_in,
                              void* d_out, int out_size, void* d_ws, size_t ws_size,
                              hipStream_t stream)
{
  (void)in_sizes; (void)n_in; (void)out_size; (void)ws_size;
  const float* X    = (const float*)d_in[0];
  const float* TMX  = (const float*)d_in[1];
  const float* TMW  = (const float*)d_in[2];
  const float* TMK  = (const float*)d_in[3];
  const float* TMV  = (const float*)d_in[4];
  const float* TMR  = (const float*)d_in[5];
  const float* TMG  = (const float*)d_in[6];
  const float* MW1  = (const float*)d_in[7];
  const float* MW2  = (const float*)d_in[8];
  const float* TD   = (const float*)d_in[9];
  const float* TDW1 = (const float*)d_in[10];
  const float* TDW2 = (const float*)d_in[11];
  const float* U    = (const float*)d_in[12];
  const float* WR   = (const float*)d_in[13];
  const float* WK   = (const float*)d_in[14];
  const float* WV   = (const float*)d_in[15];
  const float* WG   = (const float*)d_in[16];
  const float* WO   = (const float*)d_in[17];
  const float* LNG  = (const float*)d_in[18];
  const float* LNB  = (const float*)d_in[19];

  char* ws = (char*)d_ws;
  const size_t SLOT = 16777216ULL;     // B*T*C bf16 bytes
  u16* S1 = (u16*)(ws + 0 * SLOT);     // XM  -> Rb (-> rt~)
  u16* S2 = (u16*)(ws + 1 * SLOT);     // XW  -> Y lo
  u16* S3 = (u16*)(ws + 2 * SLOT);     // XK  -> Y hi
  u16* S4 = (u16*)(ws + 3 * SLOT);     // XV  -> Z
  u16* S5 = (u16*)(ws + 4 * SLOT);     // XR  -> DEC lo
  u16* S6 = (u16*)(ws + 5 * SLOT);     // XG  -> DEC hi
  u16* S7 = (u16*)(ws + 6 * SLOT);     // Kb  -> Sg lo
  u16* S8 = (u16*)(ws + 7 * SLOT);     // Vb  -> Sg hi
  u16* S9 = (u16*)(ws + 8 * SLOT);     // Gb
  char* p = ws + 9 * SLOT;
  auto alloc = [&](size_t bytes) -> void* {
    void* q = p; p += (bytes + 255) & ~(size_t)255; return q;
  };
  u16* MIXB = (u16*)alloc(8192ULL * 256 * 2);
  u16* Hb   = (u16*)alloc(8192ULL * 128 * 2);
  u16* W1T  = (u16*)alloc(256ULL * 1024 * 2);
  u16* W2T  = (u16*)alloc(5ULL * 1024 * 32 * 2);
  u16* TW1T = (u16*)alloc(128ULL * 1024 * 2);
  u16* TW2T = (u16*)alloc(1024ULL * 64 * 2);
  u16* WRb  = (u16*)alloc(1048576ULL * 2);
  u16* WKb  = (u16*)alloc(1048576ULL * 2);
  u16* WVb  = (u16*)alloc(1048576ULL * 2);
  u16* WGb  = (u16*)alloc(1048576ULL * 2);
  u16* WOb  = (u16*)alloc(1048576ULL * 2);
  float* Ab = (float*)alloc(33554432ULL);   // [bh][c][64][64] f32
  float* Pg = (float*)alloc(524288ULL);     // [bh][c][64] f32

  u16*   XM = S1; u16* XW = S2; u16* XK = S3; u16* XV = S4; u16* XR = S5; u16* XG = S6;
  u16*   Rb = S1; u16* Kb = S7; u16* Vb = S8; u16* Gb = S9;
  float* Y   = (float*)S2;    // spans S2+S3 (xw,xk dead)
  float* DEC = (float*)S5;    // spans S5+S6 (xr,xg dead)
  float* Sg  = (float*)S7;    // spans S7+S8 (kb,vb dead after s1)
  u16*   Z   = S4;            // xv dead

  // weight casts / transposes (f32 -> bf16, [N][K] K-contiguous)
  cast_k<<<1024, 256, 0, stream>>>(WR, WRb, 262144);
  cast_k<<<1024, 256, 0, stream>>>(WK, WKb, 262144);
  cast_k<<<1024, 256, 0, stream>>>(WV, WVb, 262144);
  cast_k<<<1024, 256, 0, stream>>>(WG, WGb, 262144);
  cast_k<<<1024, 256, 0, stream>>>(WO, WOb, 262144);
  tpad_k<<<1024, 256, 0, stream>>>(MW1, W1T, 1024, 160, 256LL * 1024);
  for (int f = 0; f < 5; f++)
    tpad_k<<<128, 256, 0, stream>>>(MW2 + f * 32768, W2T + f * 32768, 32, 1024, 1024LL * 32);
  tpad_k<<<512, 256, 0, stream>>>(TDW1, TW1T, 1024, 64, 128LL * 1024);
  tpad_k<<<256, 256, 0, stream>>>(TDW2, TW2T, 64, 1024, 1024LL * 64);

  // XM = x + xx*time_maa_x
  mkxm_k<<<8192, 256, 0, stream>>>(X, TMX, XM);

  // mix160 = tanh(XM @ maa_w1)        [8192,256(pad)]
  gemm_bt<1><<<dim3(64, 2), 256, 0, stream>>>(XM, 1024, W1T, 1024, MIXB, 256, 1024, nullptr, nullptr);

  // x{w,k,v,r,g} = x + xx*(tm + mix_f @ maa_w2_f)
  gemm_bt<2><<<dim3(64, 8), 256, 0, stream>>>(MIXB + 0,   256, W2T + 0*32768, 32, XW, 1024, 32, X, TMW);
  gemm_bt<2><<<dim3(64, 8), 256, 0, stream>>>(MIXB + 32,  256, W2T + 1*32768, 32, XK, 1024, 32, X, TMK);
  gemm_bt<2><<<dim3(64, 8), 256, 0, stream>>>(MIXB + 64,  256, W2T + 2*32768, 32, XV, 1024, 32, X, TMV);
  gemm_bt<2><<<dim3(64, 8), 256, 0, stream>>>(MIXB + 96,  256, W2T + 3*32768, 32, XR, 1024, 32, X, TMR);
  gemm_bt<2><<<dim3(64, 8), 256, 0, stream>>>(MIXB + 128, 256, W2T + 4*32768, 32, XG, 1024, 32, X, TMG);

  // r, k, v, g   (Rb overwrites XM slot — XM dead after MIXB gemm)
  gemm_bt<0><<<dim3(64, 8), 256, 0, stream>>>(XR, 1024, WRb, 1024, Rb, 1024, 1024, nullptr, nullptr);
  gemm_bt<0><<<dim3(64, 8), 256, 0, stream>>>(XK, 1024, WKb, 1024, Kb, 1024, 1024, nullptr, nullptr);
  gemm_bt<0><<<dim3(64, 8), 256, 0, stream>>>(XV, 1024, WVb, 1024, Vb, 1024, 1024, nullptr, nullptr);
  gemm_bt<4><<<dim3(64, 8), 256, 0, stream>>>(XG, 1024, WGb, 1024, Gb, 1024, 1024, nullptr, nullptr);

  // h = tanh(xw @ td_w1);  decay = exp(-exp(time_decay + h @ td_w2))
  gemm_bt<1><<<dim3(64, 1), 256, 0, stream>>>(XW, 1024, TW1T, 1024, Hb, 128, 1024, nullptr, nullptr);
  gemm_bt<3><<<dim3(64, 8), 256, 0, stream>>>(Hb, 128, TW2T, 64, DEC, 1024, 64, nullptr, TD);

  // WKV6 chunk-parallel scan
  wkv_s1<<<2048, 256, 0, stream>>>(Rb, Kb, Vb, DEC, U, Y, Ab, Pg);
  wkv_s2<<<256, 256, 0, stream>>>(Ab, Pg, Sg);
  wkv_s3<<<2048, 256, 0, stream>>>(Rb, Sg, Y);

  // GroupNorm(y)*g -> z
  gnorm_k<<<8192, 256, 0, stream>>>(Y, Gb, LNG, LNB, Z);

  // out = z @ Wo^T   (f32 out)
  gemm_bt<5><<<dim3(64, 8), 256, 0, stream>>>(Z, 1024, WOb, 1024, (float*)d_out, 1024, 1024, nullptr, nullptr);
}

// Round 4
// 416.241 us; speedup vs baseline: 3.0104x; 1.1601x over previous
//
#include <hip/hip_runtime.h>

typedef unsigned int u32;
typedef unsigned short u16;
typedef __attribute__((ext_vector_type(8))) short short8;
typedef __attribute__((ext_vector_type(4))) float f32x4;

__device__ __forceinline__ float b2f(u16 h){ u32 x = ((u32)h) << 16; return __builtin_bit_cast(float, x); }
__device__ __forceinline__ u16 f2b(float f){
  u32 x = __builtin_bit_cast(u32, f);
  x += 0x7fffu + ((x >> 16) & 1u);
  return (u16)(x >> 16);
}
#define LOH(u) ((u16)((u) & 0xffffu))
#define HIH(u) ((u16)((u) >> 16))

__device__ __forceinline__ void gload16(const u16* g, u16* lds){
  __builtin_amdgcn_global_load_lds((const __attribute__((address_space(1))) u32*)g,
                                   (__attribute__((address_space(3))) u32*)lds, 16, 0, 0);
}

// ---------------------------------------------------------------------------
// Generic MFMA GEMM: C[M,N] = A[M,K] * B[N,K]^T   (A,B bf16 K-contiguous)
// 128x128 tile, BK=32, 256 threads (4 waves 2x2), 16x16x32 bf16 MFMA.
// EPI: 0 bf16, 1 tanh bf16, 3 decay f32 (e_vec), 4 silu bf16, 5 plain f32
// ---------------------------------------------------------------------------
template<int EPI>
__global__ __launch_bounds__(256) void gemm_bt(
    const u16* __restrict__ A, int lda,
    const u16* __restrict__ B, int ldb,
    void* __restrict__ Cv, int ldc, int K,
    const float* __restrict__ e_vec)
{
  __shared__ u16 As[4096];
  __shared__ u16 Bs[4096];
  const int tid = threadIdx.x;
  const int wave = tid >> 6, lane = tid & 63;
  const int wr = wave >> 1, wc = wave & 1;
  const int l16 = lane & 15, kq = lane >> 4;
  const long row0 = (long)blockIdx.x * 128;
  const long col0 = (long)blockIdx.y * 128;

  f32x4 acc[4][4];
#pragma unroll
  for (int i = 0; i < 4; i++)
#pragma unroll
    for (int j = 0; j < 4; j++) acc[i][j] = (f32x4)0.0f;

  const int c0 = tid, c1 = tid + 256;
  const u16* Ag0 = A + (row0 + (c0 >> 2)) * (long)lda + (c0 & 3) * 8;
  const u16* Ag1 = A + (row0 + (c1 >> 2)) * (long)lda + (c1 & 3) * 8;
  const u16* Bg0 = B + (col0 + (c0 >> 2)) * (long)ldb + (c0 & 3) * 8;
  const u16* Bg1 = B + (col0 + (c1 >> 2)) * (long)ldb + (c1 & 3) * 8;
  u16* Al0 = &As[c0 * 8]; u16* Al1 = &As[c1 * 8];
  u16* Bl0 = &Bs[c0 * 8]; u16* Bl1 = &Bs[c1 * 8];

  for (int kk = 0; kk < K; kk += 32){
    __syncthreads();
    gload16(Ag0 + kk, Al0);
    gload16(Ag1 + kk, Al1);
    gload16(Bg0 + kk, Bl0);
    gload16(Bg1 + kk, Bl1);
    __syncthreads();
    short8 af[4], bfr[4];
#pragma unroll
    for (int mi = 0; mi < 4; mi++) af[mi]  = *(const short8*)&As[(wr*64 + mi*16 + l16)*32 + kq*8];
#pragma unroll
    for (int ni = 0; ni < 4; ni++) bfr[ni] = *(const short8*)&Bs[(wc*64 + ni*16 + l16)*32 + kq*8];
#pragma unroll
    for (int mi = 0; mi < 4; mi++)
#pragma unroll
      for (int ni = 0; ni < 4; ni++)
        acc[mi][ni] = __builtin_amdgcn_mfma_f32_16x16x32_bf16(af[mi], bfr[ni], acc[mi][ni], 0, 0, 0);
  }

#pragma unroll
  for (int mi = 0; mi < 4; mi++){
#pragma unroll
    for (int ni = 0; ni < 4; ni++){
#pragma unroll
      for (int qq = 0; qq < 4; qq++){
        const long r = row0 + wr*64 + mi*16 + kq*4 + qq;   // C/D: row=(lane>>4)*4+reg
        const long c = col0 + wc*64 + ni*16 + l16;          //      col=lane&15
        const float v = acc[mi][ni][qq];
        if (EPI == 0){
          ((u16*)Cv)[r * ldc + c] = f2b(v);
        } else if (EPI == 1){
          ((u16*)Cv)[r * ldc + c] = f2b(tanhf(v));
        } else if (EPI == 3){
          const float w = v + e_vec[c];
          ((float*)Cv)[r * ldc + c] = expf(-expf(w));
        } else if (EPI == 4){
          ((u16*)Cv)[r * ldc + c] = f2b(v / (1.0f + expf(-v)));
        } else {
          ((float*)Cv)[r * ldc + c] = v;
        }
      }
    }
  }
}

// ---------------------------------------------------------------------------
// Fused 5-way token-mix GEMM: z = blockIdx.z picks f in {w,k,v,r,g}.
// C_f = bf16( x + xx * (tm_f + MIXB_f @ W2T_f^T) ), K=32, 128x128 tiles.
// e_x = bf16(x), e_xx = bf16(x_prev - x).
// ---------------------------------------------------------------------------
struct Mix5P { const u16* ex; const u16* exx; u16* out[5]; const float* tm[5]; };

__global__ __launch_bounds__(256) void gemm_mix5(
    const u16* __restrict__ Am, const u16* __restrict__ W2T, Mix5P mp)
{
  __shared__ u16 As[4096];
  __shared__ u16 Bs[4096];
  const int tid = threadIdx.x;
  const int z = blockIdx.z;
  const u16* A = Am + z * 32;                 // lda 256
  const u16* B = W2T + z * 32768;             // ldb 32
  u16* C = mp.out[z];
  const float* tm = mp.tm[z];
  const int wave = tid >> 6, lane = tid & 63;
  const int wr = wave >> 1, wc = wave & 1;
  const int l16 = lane & 15, kq = lane >> 4;
  const long row0 = (long)blockIdx.x * 128;
  const long col0 = (long)blockIdx.y * 128;

  f32x4 acc[4][4];
#pragma unroll
  for (int i = 0; i < 4; i++)
#pragma unroll
    for (int j = 0; j < 4; j++) acc[i][j] = (f32x4)0.0f;

  const int c0 = tid, c1 = tid + 256;
  gload16(A + (row0 + (c0 >> 2)) * 256 + (c0 & 3) * 8, &As[c0 * 8]);
  gload16(A + (row0 + (c1 >> 2)) * 256 + (c1 & 3) * 8, &As[c1 * 8]);
  gload16(B + (col0 + (c0 >> 2)) * 32 + (c0 & 3) * 8, &Bs[c0 * 8]);
  gload16(B + (col0 + (c1 >> 2)) * 32 + (c1 & 3) * 8, &Bs[c1 * 8]);
  __syncthreads();
  short8 af[4], bfr[4];
#pragma unroll
  for (int mi = 0; mi < 4; mi++) af[mi]  = *(const short8*)&As[(wr*64 + mi*16 + l16)*32 + kq*8];
#pragma unroll
  for (int ni = 0; ni < 4; ni++) bfr[ni] = *(const short8*)&Bs[(wc*64 + ni*16 + l16)*32 + kq*8];
#pragma unroll
  for (int mi = 0; mi < 4; mi++)
#pragma unroll
    for (int ni = 0; ni < 4; ni++)
      acc[mi][ni] = __builtin_amdgcn_mfma_f32_16x16x32_bf16(af[mi], bfr[ni], acc[mi][ni], 0, 0, 0);

#pragma unroll
  for (int mi = 0; mi < 4; mi++){
#pragma unroll
    for (int ni = 0; ni < 4; ni++){
#pragma unroll
      for (int qq = 0; qq < 4; qq++){
        const long r = row0 + wr*64 + mi*16 + kq*4 + qq;
        const long c = col0 + wc*64 + ni*16 + l16;
        const float xc = b2f(mp.ex[r * 1024 + c]);
        const float xx = b2f(mp.exx[r * 1024 + c]);
        C[r * 1024 + c] = f2b(xc + xx * (tm[c] + acc[mi][ni][qq]));
      }
    }
  }
}

// ---------------------------------------------------------------------------
// XM = bf16(x + (xp-x)*tmx);  XBF = bf16(x);  XX = bf16(xp - x)
// ---------------------------------------------------------------------------
__global__ __launch_bounds__(256) void mkxm_k(const float* __restrict__ X,
    const float* __restrict__ tmx, u16* __restrict__ XM,
    u16* __restrict__ XBF, u16* __restrict__ XXo)
{
  const long idx = (long)blockIdx.x * 256 + threadIdx.x;
  const long m = idx >> 8;
  const int c4 = (int)(idx & 255) * 4;
  const float4 x = *(const float4*)(X + m * 1024 + c4);
  float4 p = make_float4(0.f, 0.f, 0.f, 0.f);
  if ((m & 2047) != 0) p = *(const float4*)(X + (m - 1) * 1024 + c4);
  const float4 t = *(const float4*)(tmx + c4);
  ushort4 o;
  o.x = f2b(x.x + (p.x - x.x) * t.x);
  o.y = f2b(x.y + (p.y - x.y) * t.y);
  o.z = f2b(x.z + (p.z - x.z) * t.z);
  o.w = f2b(x.w + (p.w - x.w) * t.w);
  *(ushort4*)(XM + m * 1024 + c4) = o;
  ushort4 ob; ob.x = f2b(x.x); ob.y = f2b(x.y); ob.z = f2b(x.z); ob.w = f2b(x.w);
  *(ushort4*)(XBF + m * 1024 + c4) = ob;
  ushort4 ox; ox.x = f2b(p.x - x.x); ox.y = f2b(p.y - x.y); ox.z = f2b(p.z - x.z); ox.w = f2b(p.w - x.w);
  *(ushort4*)(XXo + m * 1024 + c4) = ox;
}

// ---------------------------------------------------------------------------
// 5 weight casts in one launch (blockIdx.y = which)
// ---------------------------------------------------------------------------
struct Cast5P { const float* s[5]; u16* d[5]; };
__global__ __launch_bounds__(256) void cast5_k(Cast5P cp)
{
  const int w = blockIdx.y;
  const long i = (long)blockIdx.x * 256 + threadIdx.x;
  const float4 v = ((const float4*)cp.s[w])[i];
  ushort4 o; o.x = f2b(v.x); o.y = f2b(v.y); o.z = f2b(v.z); o.w = f2b(v.w);
  ((ushort4*)cp.d[w])[i] = o;
}

// ---------------------------------------------------------------------------
// dst[n][k] = bf16( (n < Ccols) ? src[k][n] : 0 )   dst [dstR][R], idx = n*R+k
// ---------------------------------------------------------------------------
__global__ __launch_bounds__(256) void tpad_k(const float* __restrict__ src,
    u16* __restrict__ dst, int R, int Ccols, long total)
{
  const long idx = (long)blockIdx.x * 256 + threadIdx.x;
  if (idx >= total) return;
  const int k = (int)(idx % R);
  const int n = (int)(idx / R);
  dst[idx] = (n < Ccols) ? f2b(src[(long)k * Ccols + n]) : (u16)0;
}

// ---------------------------------------------------------------------------
// MW2 [5][32][1024] -> W2T [5][1024][32] bf16, one launch
// ---------------------------------------------------------------------------
__global__ __launch_bounds__(256) void tpw2_k(const float* __restrict__ src,
    u16* __restrict__ dst)
{
  const int n = blockIdx.x * 256 + threadIdx.x;    // < 163840
  const int k = n & 31;
  const int col = (n >> 5) & 1023;
  const int f = n >> 15;
  dst[n] = f2b(src[f * 32768 + k * 1024 + col]);
}

// ---------------------------------------------------------------------------
// WKV6 stage 1 (MFMA). Block per (b,h,chunk).
//  M = r̃·k̃ᵀ (masked s<i), Y = M·V + diag·v, A = k̃ᵀ·V, r̃ back to Rg, Pg out.
// ---------------------------------------------------------------------------
__global__ __launch_bounds__(256) void wkv_s1(
    u16* __restrict__ Rg, const u16* __restrict__ Kg, const u16* __restrict__ Vg,
    const float* __restrict__ Dg, const float* __restrict__ Ug,
    float* __restrict__ Yg, float* __restrict__ Ag, float* __restrict__ Pg)
{
  __shared__ u16 RT_[64 * 72];     // r -> r̃  [i][k]
  __shared__ u16 KT_[64 * 72];     // k -> k̃  [s][k]
  __shared__ u16 KTT_[64 * 72];    // k̃ᵀ [k][s]
  __shared__ u16 V_[64 * 72];      // V [s][j]
  __shared__ u16 VT_[64 * 72];     // Vᵀ [j][s]
  __shared__ char UD_[64 * 68 * 4];// D f32 [i][68], then M u16 [i][72]
  __shared__ float us_[64];
  __shared__ float dg4_[256];
  __shared__ float dg_[64];
  float* D_ = (float*)UD_;
  u16*  M_  = (u16*)UD_;

  const int tid = threadIdx.x;
  const int bh = blockIdx.x >> 5, ch = blockIdx.x & 31;
  const int b = bh >> 4, h = bh & 15, cb = h * 64;
  const long rowb = (long)b * 2048 + ch * 64;

  if (tid < 64) us_[tid] = Ug[cb + tid];

  const int iS = tid >> 2, sg = tid & 3;
  // ---- P0: stage r,k,v(,vT),d
  {
    const long go = (rowb + iS) * 1024 + cb + sg * 16;
    uint4 a0 = *(const uint4*)(Rg + go);
    uint4 a1 = *(const uint4*)(Rg + go + 8);
    u32* rd = (u32*)&RT_[iS * 72 + sg * 16];
    rd[0]=a0.x; rd[1]=a0.y; rd[2]=a0.z; rd[3]=a0.w;
    rd[4]=a1.x; rd[5]=a1.y; rd[6]=a1.z; rd[7]=a1.w;
    a0 = *(const uint4*)(Kg + go); a1 = *(const uint4*)(Kg + go + 8);
    u32* kd = (u32*)&KT_[iS * 72 + sg * 16];
    kd[0]=a0.x; kd[1]=a0.y; kd[2]=a0.z; kd[3]=a0.w;
    kd[4]=a1.x; kd[5]=a1.y; kd[6]=a1.z; kd[7]=a1.w;
    a0 = *(const uint4*)(Vg + go); a1 = *(const uint4*)(Vg + go + 8);
    u32* vd = (u32*)&V_[iS * 72 + sg * 16];
    vd[0]=a0.x; vd[1]=a0.y; vd[2]=a0.z; vd[3]=a0.w;
    vd[4]=a1.x; vd[5]=a1.y; vd[6]=a1.z; vd[7]=a1.w;
    const u32 vw[8] = {a0.x,a0.y,a0.z,a0.w,a1.x,a1.y,a1.z,a1.w};
#pragma unroll
    for (int e = 0; e < 8; e++){
      VT_[(sg*16 + 2*e    ) * 72 + iS] = LOH(vw[e]);
      VT_[(sg*16 + 2*e + 1) * 72 + iS] = HIH(vw[e]);
    }
    const float4* dsrc = (const float4*)(Dg + go);
    float4* dd = (float4*)&D_[iS * 68 + sg * 16];
    dd[0]=dsrc[0]; dd[1]=dsrc[1]; dd[2]=dsrc[2]; dd[3]=dsrc[3];
  }
  __syncthreads();
  // ---- P0b: diag partials with RAW r,k
  {
    const int i = tid & 63, q = tid >> 6;
    const u32* rr = (const u32*)&RT_[i * 72 + q * 16];
    const u32* kr = (const u32*)&KT_[i * 72 + q * 16];
    const float* up = &us_[q * 16];
    float ds = 0.0f;
#pragma unroll
    for (int e = 0; e < 8; e++){
      ds += b2f(LOH(rr[e])) * up[2*e]   * b2f(LOH(kr[e]));
      ds += b2f(HIH(rr[e])) * up[2*e+1] * b2f(HIH(kr[e]));
    }
    dg4_[i * 4 + q] = ds;
  }
  __syncthreads();
  // ---- P0c: prefix decay; RT->r̃, KT->k̃ (and KTT); diag finalize; Pg
  if (tid < 64){
    const int k = tid;
    dg_[k] = dg4_[k*4] + dg4_[k*4+1] + dg4_[k*4+2] + dg4_[k*4+3];
    float pz = 1.0f;
#pragma unroll 4
    for (int i = 0; i < 64; i++){
      const float d = D_[i * 68 + k];
      const int ro = i * 72 + k;
      RT_[ro] = f2b(b2f(RT_[ro]) * pz);
      pz *= d;
      const u16 kb = f2b(b2f(KT_[ro]) * (1.0f / pz));
      KT_[ro] = kb;
      KTT_[k * 72 + i] = kb;
    }
    Pg[((long)bh * 32 + ch) * 64 + k] = pz;
  }
  __syncthreads();
  // ---- writeback r̃ to Rg
  {
    const u32* rr = (const u32*)&RT_[iS * 72 + sg * 16];
    u32* out = (u32*)(Rg + (rowb + iS) * 1024 + cb + sg * 16);
#pragma unroll
    for (int e = 0; e < 8; e++) out[e] = rr[e];
  }
  const int wave = tid >> 6, lane = tid & 63;
  const int wr = wave >> 1, wc = wave & 1;
  const int l16 = lane & 15, kq = lane >> 4;
  // ---- P2: M = r̃·k̃ᵀ, mask s<i, store bf16 to M_
  {
    f32x4 acc[2][2];
#pragma unroll
    for (int a = 0; a < 2; a++)
#pragma unroll
      for (int c = 0; c < 2; c++) acc[a][c] = (f32x4)0.0f;
#pragma unroll
    for (int ks = 0; ks < 2; ks++){
      short8 af[2], bf[2];
#pragma unroll
      for (int mi = 0; mi < 2; mi++) af[mi] = *(const short8*)&RT_[(wr*32 + mi*16 + l16)*72 + ks*32 + kq*8];
#pragma unroll
      for (int ni = 0; ni < 2; ni++) bf[ni] = *(const short8*)&KT_[(wc*32 + ni*16 + l16)*72 + ks*32 + kq*8];
#pragma unroll
      for (int mi = 0; mi < 2; mi++)
#pragma unroll
        for (int ni = 0; ni < 2; ni++)
          acc[mi][ni] = __builtin_amdgcn_mfma_f32_16x16x32_bf16(af[mi], bf[ni], acc[mi][ni], 0, 0, 0);
    }
    __syncthreads();    // D_ dead; M_ union becomes valid
#pragma unroll
    for (int mi = 0; mi < 2; mi++)
#pragma unroll
      for (int ni = 0; ni < 2; ni++)
#pragma unroll
        for (int qq = 0; qq < 4; qq++){
          const int ii = wr*32 + mi*16 + kq*4 + qq;
          const int ss = wc*32 + ni*16 + l16;
          M_[ii * 72 + ss] = f2b(ss < ii ? acc[mi][ni][qq] : 0.0f);
        }
  }
  __syncthreads();
  // ---- P3+P4: Y = M·V + diag·v ; A = k̃ᵀ·V
  {
    f32x4 accY[2][2], accA[2][2];
#pragma unroll
    for (int a = 0; a < 2; a++)
#pragma unroll
      for (int c = 0; c < 2; c++){ accY[a][c] = (f32x4)0.0f; accA[a][c] = (f32x4)0.0f; }
#pragma unroll
    for (int ks = 0; ks < 2; ks++){
      short8 am[2], ak[2], bv[2];
#pragma unroll
      for (int mi = 0; mi < 2; mi++){
        am[mi] = *(const short8*)&M_[(wr*32 + mi*16 + l16)*72 + ks*32 + kq*8];
        ak[mi] = *(const short8*)&KTT_[(wr*32 + mi*16 + l16)*72 + ks*32 + kq*8];
      }
#pragma unroll
      for (int ni = 0; ni < 2; ni++) bv[ni] = *(const short8*)&VT_[(wc*32 + ni*16 + l16)*72 + ks*32 + kq*8];
#pragma unroll
      for (int mi = 0; mi < 2; mi++)
#pragma unroll
        for (int ni = 0; ni < 2; ni++){
          accY[mi][ni] = __builtin_amdgcn_mfma_f32_16x16x32_bf16(am[mi], bv[ni], accY[mi][ni], 0, 0, 0);
          accA[mi][ni] = __builtin_amdgcn_mfma_f32_16x16x32_bf16(ak[mi], bv[ni], accA[mi][ni], 0, 0, 0);
        }
    }
    float* abase = Ag + ((long)bh * 32 + ch) * 4096;
#pragma unroll
    for (int mi = 0; mi < 2; mi++)
#pragma unroll
      for (int ni = 0; ni < 2; ni++)
#pragma unroll
        for (int qq = 0; qq < 4; qq++){
          const int ii = wr*32 + mi*16 + kq*4 + qq;
          const int jj = wc*32 + ni*16 + l16;
          const float yv = accY[mi][ni][qq] + dg_[ii] * b2f(V_[ii * 72 + jj]);
          Yg[(rowb + ii) * 1024 + cb + jj] = yv;
          abase[ii * 64 + jj] = accA[mi][ni][qq];
        }
  }
}

// ---------------------------------------------------------------------------
// WKV6 stage 2 — inter-chunk recurrence S_{c+1} = ps_c*(S_c + A_c).
// ---------------------------------------------------------------------------
__global__ __launch_bounds__(256) void wkv_s2(
    const float* __restrict__ Ag, const float* __restrict__ Pg, float* __restrict__ Sg)
{
  const int tid = threadIdx.x;
  const int bh = blockIdx.x >> 2, kq = blockIdx.x & 3;
  const int kk = tid >> 4, jo = tid & 15;
  const int krow = kq * 16 + kk;
  const long base = (long)bh * 32;
  float4 S = make_float4(0.f, 0.f, 0.f, 0.f);
  for (int c = 0; c < 32; c++){
    const long mo = (base + c) * 4096 + krow * 64 + jo * 4;
    *(float4*)(Sg + mo) = S;
    const float4 a = *(const float4*)(Ag + mo);
    const float ps = Pg[(base + c) * 64 + krow];
    S.x = ps * (S.x + a.x); S.y = ps * (S.y + a.y);
    S.z = ps * (S.z + a.z); S.w = ps * (S.w + a.w);
  }
}

// ---------------------------------------------------------------------------
// WKV6 stage 3 — cross term: Yg += rt~ . S_chunkstart.  Block per (bh,chunk).
// ---------------------------------------------------------------------------
__global__ __launch_bounds__(256) void wkv_s3(
    const u16* __restrict__ Rtg, const float* __restrict__ Sg, float* __restrict__ Yg)
{
  __shared__ float Ss[4096];        // [k][j]
  __shared__ u16 RTs[64 * 66];
  const int tid = threadIdx.x;
  const int bh = blockIdx.x >> 5, ch = blockIdx.x & 31;
  if (ch == 0) return;
  const int b = bh >> 4, h = bh & 15, cb = h * 64;
  const long rowb = (long)b * 2048 + ch * 64;

  {
    const float4* sp = (const float4*)(Sg + ((long)bh * 32 + ch) * 4096);
    float4* sd = (float4*)Ss;
#pragma unroll
    for (int e = 0; e < 4; e++) sd[tid + e * 256] = sp[tid + e * 256];
  }
  {
    const int iS = tid >> 2, sg4 = tid & 3;
    const u32* src = (const u32*)(Rtg + (rowb + iS) * 1024 + cb + sg4 * 16);
    u32* dst = (u32*)&RTs[iS * 66 + sg4 * 16];
#pragma unroll
    for (int e = 0; e < 8; e++) dst[e] = src[e];
  }
  __syncthreads();

  const int i_ = tid & 63, q = tid >> 6, jb = q * 16;
  float rt[64];
  {
    const u32* rr = (const u32*)&RTs[i_ * 66];
#pragma unroll
    for (int kk = 0; kk < 32; kk++){
      const u32 u = rr[kk];
      rt[2*kk] = b2f(LOH(u)); rt[2*kk+1] = b2f(HIH(u));
    }
  }
  float* yo = Yg + (rowb + i_) * 1024 + cb + jb;
  float y[16];
#pragma unroll
  for (int j4 = 0; j4 < 4; j4++){
    const float4 v = *(const float4*)(yo + 4*j4);
    y[4*j4] = v.x; y[4*j4+1] = v.y; y[4*j4+2] = v.z; y[4*j4+3] = v.w;
  }
#pragma unroll
  for (int k = 0; k < 64; k++){
    const float rk = rt[k];
    const float4* sr = (const float4*)&Ss[k * 64 + jb];
#pragma unroll
    for (int j4 = 0; j4 < 4; j4++){
      const float4 sv = sr[j4];
      y[4*j4+0] += rk*sv.x; y[4*j4+1] += rk*sv.y; y[4*j4+2] += rk*sv.z; y[4*j4+3] += rk*sv.w;
    }
  }
#pragma unroll
  for (int j4 = 0; j4 < 4; j4++)
    *(float4*)(yo + 4*j4) = make_float4(y[4*j4], y[4*j4+1], y[4*j4+2], y[4*j4+3]);
}

// ---------------------------------------------------------------------------
// GroupNorm over each head's 64 channels, then * g   (one block per bt row)
// ---------------------------------------------------------------------------
__global__ __launch_bounds__(256) void gnorm_k(const float* __restrict__ Y,
    const u16* __restrict__ G, const float* __restrict__ lng,
    const float* __restrict__ lnb, u16* __restrict__ Z)
{
  const long row = blockIdx.x;
  const int tid = threadIdx.x;
  const int hh = tid >> 4, l = tid & 15;
  const int c = hh * 64 + l * 4;
  const float4 v = *(const float4*)(Y + row * 1024 + c);
  float s = v.x + v.y + v.z + v.w;
  float sq = v.x*v.x + v.y*v.y + v.z*v.z + v.w*v.w;
#pragma unroll
  for (int off = 1; off < 16; off <<= 1){ s += __shfl_xor(s, off); sq += __shfl_xor(sq, off); }
  const float mean = s * 0.015625f;
  const float var = sq * 0.015625f - mean * mean;
  const float rstd = rsqrtf(var + 6.4e-4f);   // eps = 1e-5 * 64
  const uint2 gg = *(const uint2*)(G + row * 1024 + c);
  const float4 lg = *(const float4*)(lng + c);
  const float4 lb = *(const float4*)(lnb + c);
  const float vv[4] = {v.x, v.y, v.z, v.w};
  const float lgs[4] = {lg.x, lg.y, lg.z, lg.w};
  const float lbs[4] = {lb.x, lb.y, lb.z, lb.w};
  const u32 gs[2] = {gg.x, gg.y};
  ushort4 o;
  u16* op = (u16*)&o;
#pragma unroll
  for (int e = 0; e < 4; e++){
    const float gv = b2f((e & 1) ? HIH(gs[e >> 1]) : LOH(gs[e >> 1]));
    op[e] = f2b(((vv[e] - mean) * rstd * lgs[e] + lbs[e]) * gv);
  }
  *(ushort4*)(Z + row * 1024 + c) = o;
}

// ---------------------------------------------------------------------------
extern "C" void kernel_launch(void* const* d_in, const int* in_sizes, int n_in,
                              void* d_out, int out_size, void* d_ws, size_t ws_size,
                              hipStream_t stream)
{
  (void)in_sizes; (void)n_in; (void)out_size; (void)ws_size;
  const float* X    = (const float*)d_in[0];
  const float* TMX  = (const float*)d_in[1];
  const float* TMW  = (const float*)d_in[2];
  const float* TMK  = (const float*)d_in[3];
  const float* TMV  = (const float*)d_in[4];
  const float* TMR  = (const float*)d_in[5];
  const float* TMG  = (const float*)d_in[6];
  const float* MW1  = (const float*)d_in[7];
  const float* MW2  = (const float*)d_in[8];
  const float* TD   = (const float*)d_in[9];
  const float* TDW1 = (const float*)d_in[10];
  const float* TDW2 = (const float*)d_in[11];
  const float* U    = (const float*)d_in[12];
  const float* WR   = (const float*)d_in[13];
  const float* WK   = (const float*)d_in[14];
  const float* WV   = (const float*)d_in[15];
  const float* WG   = (const float*)d_in[16];
  const float* WO   = (const float*)d_in[17];
  const float* LNG  = (const float*)d_in[18];
  const float* LNB  = (const float*)d_in[19];

  char* ws = (char*)d_ws;
  const size_t SLOT = 16777216ULL;     // B*T*C bf16 bytes
  u16* S1 = (u16*)(ws + 0 * SLOT);     // XM  -> Rb (-> rt~)
  u16* S2 = (u16*)(ws + 1 * SLOT);     // XW  -> Y lo
  u16* S3 = (u16*)(ws + 2 * SLOT);     // XK  -> Y hi
  u16* S4 = (u16*)(ws + 3 * SLOT);     // XV  -> Z
  u16* S5 = (u16*)(ws + 4 * SLOT);     // XR  -> DEC lo
  u16* S6 = (u16*)(ws + 5 * SLOT);     // XG  -> DEC hi
  u16* S7 = (u16*)(ws + 6 * SLOT);     // XBF -> Kb -> Sg lo
  u16* S8 = (u16*)(ws + 7 * SLOT);     // XX  -> Vb -> Sg hi
  u16* S9 = (u16*)(ws + 8 * SLOT);     // Gb
  char* p = ws + 9 * SLOT;
  auto alloc = [&](size_t bytes) -> void* {
    void* q = p; p += (bytes + 255) & ~(size_t)255; return q;
  };
  u16* MIXB = (u16*)alloc(8192ULL * 256 * 2);
  u16* Hb   = (u16*)alloc(8192ULL * 128 * 2);
  u16* W1T  = (u16*)alloc(256ULL * 1024 * 2);
  u16* W2T  = (u16*)alloc(5ULL * 1024 * 32 * 2);
  u16* TW1T = (u16*)alloc(128ULL * 1024 * 2);
  u16* TW2T = (u16*)alloc(1024ULL * 64 * 2);
  u16* WRb  = (u16*)alloc(1048576ULL * 2);
  u16* WKb  = (u16*)alloc(1048576ULL * 2);
  u16* WVb  = (u16*)alloc(1048576ULL * 2);
  u16* WGb  = (u16*)alloc(1048576ULL * 2);
  u16* WOb  = (u16*)alloc(1048576ULL * 2);
  float* Ab = (float*)alloc(33554432ULL);   // [bh][c][64][64] f32
  float* Pg = (float*)alloc(524288ULL);     // [bh][c][64] f32

  u16*   XM = S1; u16* XW = S2; u16* XK = S3; u16* XV = S4; u16* XR = S5; u16* XG = S6;
  u16*   XBF = S7; u16* XX = S8;
  u16*   Rb = S1; u16* Kb = S7; u16* Vb = S8; u16* Gb = S9;
  float* Y   = (float*)S2;    // spans S2+S3 (xw,xk dead)
  float* DEC = (float*)S5;    // spans S5+S6 (xr,xg dead)
  float* Sg  = (float*)S7;    // spans S7+S8 (kb,vb dead after s1)
  u16*   Z   = S4;            // xv dead

  // weight casts / transposes (f32 -> bf16, [N][K] K-contiguous)
  Cast5P cp;
  cp.s[0]=WR; cp.s[1]=WK; cp.s[2]=WV; cp.s[3]=WG; cp.s[4]=WO;
  cp.d[0]=WRb; cp.d[1]=WKb; cp.d[2]=WVb; cp.d[3]=WGb; cp.d[4]=WOb;
  cast5_k<<<dim3(1024, 5), 256, 0, stream>>>(cp);
  tpad_k<<<1024, 256, 0, stream>>>(MW1, W1T, 1024, 160, 256LL * 1024);
  tpw2_k<<<640, 256, 0, stream>>>(MW2, W2T);
  tpad_k<<<512, 256, 0, stream>>>(TDW1, TW1T, 1024, 64, 128LL * 1024);
  tpad_k<<<256, 256, 0, stream>>>(TDW2, TW2T, 64, 1024, 1024LL * 64);

  // XM / XBF / XX
  mkxm_k<<<8192, 256, 0, stream>>>(X, TMX, XM, XBF, XX);

  // mix160 = tanh(XM @ maa_w1)        [8192,256(pad)]
  gemm_bt<1><<<dim3(64, 2), 256, 0, stream>>>(XM, 1024, W1T, 1024, MIXB, 256, 1024, nullptr);

  // x{w,k,v,r,g} = x + xx*(tm + mix_f @ maa_w2_f)   — one fused launch
  Mix5P mp;
  mp.ex = XBF; mp.exx = XX;
  mp.out[0]=XW; mp.out[1]=XK; mp.out[2]=XV; mp.out[3]=XR; mp.out[4]=XG;
  mp.tm[0]=TMW; mp.tm[1]=TMK; mp.tm[2]=TMV; mp.tm[3]=TMR; mp.tm[4]=TMG;
  gemm_mix5<<<dim3(64, 8, 5), 256, 0, stream>>>(MIXB, W2T, mp);

  // r, k, v, g   (Rb overwrites XM slot; Kb/Vb overwrite XBF/XX — all dead)
  gemm_bt<0><<<dim3(64, 8), 256, 0, stream>>>(XR, 1024, WRb, 1024, Rb, 1024, 1024, nullptr);
  gemm_bt<0><<<dim3(64, 8), 256, 0, stream>>>(XK, 1024, WKb, 1024, Kb, 1024, 1024, nullptr);
  gemm_bt<0><<<dim3(64, 8), 256, 0, stream>>>(XV, 1024, WVb, 1024, Vb, 1024, 1024, nullptr);
  gemm_bt<4><<<dim3(64, 8), 256, 0, stream>>>(XG, 1024, WGb, 1024, Gb, 1024, 1024, nullptr);

  // h = tanh(xw @ td_w1);  decay = exp(-exp(time_decay + h @ td_w2))
  gemm_bt<1><<<dim3(64, 1), 256, 0, stream>>>(XW, 1024, TW1T, 1024, Hb, 128, 1024, nullptr);
  gemm_bt<3><<<dim3(64, 8), 256, 0, stream>>>(Hb, 128, TW2T, 64, DEC, 1024, 64, TD);

  // WKV6 chunk-parallel scan
  wkv_s1<<<2048, 256, 0, stream>>>(Rb, Kb, Vb, DEC, U, Y, Ab, Pg);
  wkv_s2<<<256, 256, 0, stream>>>(Ab, Pg, Sg);
  wkv_s3<<<2048, 256, 0, stream>>>(Rb, Sg, Y);

  // GroupNorm(y)*g -> z
  gnorm_k<<<8192, 256, 0, stream>>>(Y, Gb, LNG, LNB, Z);

  // out = z @ Wo^T   (f32 out)
  gemm_bt<5><<<dim3(64, 8), 256, 0, stream>>>(Z, 1024, WOb, 1024, (float*)d_out, 1024, 1024, nullptr);
}

// Round 6
// 377.884 us; speedup vs baseline: 3.3160x; 1.1015x over previous
//
#include <hip/hip_runtime.h>

typedef unsigned int u32;
typedef unsigned short u16;
typedef __attribute__((ext_vector_type(8))) short short8;
typedef __attribute__((ext_vector_type(4))) float f32x4;

__device__ __forceinline__ float b2f(u16 h){ u32 x = ((u32)h) << 16; return __builtin_bit_cast(float, x); }
__device__ __forceinline__ u16 f2b(float f){
  u32 x = __builtin_bit_cast(u32, f);
  x += 0x7fffu + ((x >> 16) & 1u);
  return (u16)(x >> 16);
}
#define LOH(u) ((u16)((u) & 0xffffu))
#define HIH(u) ((u16)((u) >> 16))

__device__ __forceinline__ void gload16(const u16* g, u16* lds){
  __builtin_amdgcn_global_load_lds((const __attribute__((address_space(1))) u32*)g,
                                   (__attribute__((address_space(3))) u32*)lds, 16, 0, 0);
}

// ---------------------------------------------------------------------------
// Generic MFMA GEMM: C[M,N] = A[M,K] * B[N,K]^T   (A,B bf16 K-contiguous)
// 128x128 tile, BK=32, 256 threads (4 waves 2x2), 16x16x32 bf16 MFMA.
// EPI: 0 bf16, 1 tanh bf16, 3 decay f32 (e_vec), 4 silu bf16, 5 plain f32
// ---------------------------------------------------------------------------
template<int EPI>
__global__ __launch_bounds__(256) void gemm_bt(
    const u16* __restrict__ A, int lda,
    const u16* __restrict__ B, int ldb,
    void* __restrict__ Cv, int ldc, int K,
    const float* __restrict__ e_vec)
{
  __shared__ u16 As[4096];
  __shared__ u16 Bs[4096];
  const int tid = threadIdx.x;
  const int wave = tid >> 6, lane = tid & 63;
  const int wr = wave >> 1, wc = wave & 1;
  const int l16 = lane & 15, kq = lane >> 4;
  const long row0 = (long)blockIdx.x * 128;
  const long col0 = (long)blockIdx.y * 128;

  f32x4 acc[4][4];
#pragma unroll
  for (int i = 0; i < 4; i++)
#pragma unroll
    for (int j = 0; j < 4; j++) acc[i][j] = (f32x4)0.0f;

  const int c0 = tid, c1 = tid + 256;
  const u16* Ag0 = A + (row0 + (c0 >> 2)) * (long)lda + (c0 & 3) * 8;
  const u16* Ag1 = A + (row0 + (c1 >> 2)) * (long)lda + (c1 & 3) * 8;
  const u16* Bg0 = B + (col0 + (c0 >> 2)) * (long)ldb + (c0 & 3) * 8;
  const u16* Bg1 = B + (col0 + (c1 >> 2)) * (long)ldb + (c1 & 3) * 8;
  u16* Al0 = &As[c0 * 8]; u16* Al1 = &As[c1 * 8];
  u16* Bl0 = &Bs[c0 * 8]; u16* Bl1 = &Bs[c1 * 8];

  for (int kk = 0; kk < K; kk += 32){
    __syncthreads();
    gload16(Ag0 + kk, Al0);
    gload16(Ag1 + kk, Al1);
    gload16(Bg0 + kk, Bl0);
    gload16(Bg1 + kk, Bl1);
    __syncthreads();
    short8 af[4], bfr[4];
#pragma unroll
    for (int mi = 0; mi < 4; mi++) af[mi]  = *(const short8*)&As[(wr*64 + mi*16 + l16)*32 + kq*8];
#pragma unroll
    for (int ni = 0; ni < 4; ni++) bfr[ni] = *(const short8*)&Bs[(wc*64 + ni*16 + l16)*32 + kq*8];
#pragma unroll
    for (int mi = 0; mi < 4; mi++)
#pragma unroll
      for (int ni = 0; ni < 4; ni++)
        acc[mi][ni] = __builtin_amdgcn_mfma_f32_16x16x32_bf16(af[mi], bfr[ni], acc[mi][ni], 0, 0, 0);
  }

#pragma unroll
  for (int mi = 0; mi < 4; mi++){
#pragma unroll
    for (int qq = 0; qq < 4; qq++){
      const long r = row0 + wr*64 + mi*16 + kq*4 + qq;   // C/D: row=(lane>>4)*4+reg
#pragma unroll
      for (int ni = 0; ni < 4; ni++){
        const long c = col0 + wc*64 + ni*16 + l16;        //      col=lane&15
        const float v = acc[mi][ni][qq];
        if (EPI == 0){
          ((u16*)Cv)[r * ldc + c] = f2b(v);
        } else if (EPI == 1){
          ((u16*)Cv)[r * ldc + c] = f2b(tanhf(v));
        } else if (EPI == 3){
          const float w = v + e_vec[c];
          ((float*)Cv)[r * ldc + c] = expf(-expf(w));
        } else if (EPI == 4){
          ((u16*)Cv)[r * ldc + c] = f2b(v / (1.0f + expf(-v)));
        } else {
          ((float*)Cv)[r * ldc + c] = v;
        }
      }
    }
  }
}

// ---------------------------------------------------------------------------
// 4 big GEMMs (r,k,v,g) fused in one dispatch: z picks the pair; z==3 -> SiLU.
// All M=8192, N=1024, K=1024, lda=ldb=ldc=1024.
// ---------------------------------------------------------------------------
struct G4P { const u16* A[4]; const u16* B[4]; u16* C[4]; };

__global__ __launch_bounds__(256) void gemm4_k(G4P gp)
{
  __shared__ u16 As[4096];
  __shared__ u16 Bs[4096];
  const int tid = threadIdx.x;
  const int z = blockIdx.z;
  const u16* __restrict__ A = gp.A[z];
  const u16* __restrict__ B = gp.B[z];
  u16* __restrict__ C = gp.C[z];
  const int wave = tid >> 6, lane = tid & 63;
  const int wr = wave >> 1, wc = wave & 1;
  const int l16 = lane & 15, kq = lane >> 4;
  const long row0 = (long)blockIdx.x * 128;
  const long col0 = (long)blockIdx.y * 128;

  f32x4 acc[4][4];
#pragma unroll
  for (int i = 0; i < 4; i++)
#pragma unroll
    for (int j = 0; j < 4; j++) acc[i][j] = (f32x4)0.0f;

  const int c0 = tid, c1 = tid + 256;
  const u16* Ag0 = A + (row0 + (c0 >> 2)) * 1024 + (c0 & 3) * 8;
  const u16* Ag1 = A + (row0 + (c1 >> 2)) * 1024 + (c1 & 3) * 8;
  const u16* Bg0 = B + (col0 + (c0 >> 2)) * 1024 + (c0 & 3) * 8;
  const u16* Bg1 = B + (col0 + (c1 >> 2)) * 1024 + (c1 & 3) * 8;
  u16* Al0 = &As[c0 * 8]; u16* Al1 = &As[c1 * 8];
  u16* Bl0 = &Bs[c0 * 8]; u16* Bl1 = &Bs[c1 * 8];

  for (int kk = 0; kk < 1024; kk += 32){
    __syncthreads();
    gload16(Ag0 + kk, Al0);
    gload16(Ag1 + kk, Al1);
    gload16(Bg0 + kk, Bl0);
    gload16(Bg1 + kk, Bl1);
    __syncthreads();
    short8 af[4], bfr[4];
#pragma unroll
    for (int mi = 0; mi < 4; mi++) af[mi]  = *(const short8*)&As[(wr*64 + mi*16 + l16)*32 + kq*8];
#pragma unroll
    for (int ni = 0; ni < 4; ni++) bfr[ni] = *(const short8*)&Bs[(wc*64 + ni*16 + l16)*32 + kq*8];
#pragma unroll
    for (int mi = 0; mi < 4; mi++)
#pragma unroll
      for (int ni = 0; ni < 4; ni++)
        acc[mi][ni] = __builtin_amdgcn_mfma_f32_16x16x32_bf16(af[mi], bfr[ni], acc[mi][ni], 0, 0, 0);
  }

  const bool SILU = (z == 3);
#pragma unroll
  for (int mi = 0; mi < 4; mi++){
#pragma unroll
    for (int qq = 0; qq < 4; qq++){
      const long r = row0 + wr*64 + mi*16 + kq*4 + qq;
      u16* crow = C + r * 1024 + col0 + wc*64 + l16;
#pragma unroll
      for (int ni = 0; ni < 4; ni++){
        float v = acc[mi][ni][qq];
        if (SILU) v = v / (1.0f + expf(-v));
        crow[ni * 16] = f2b(v);
      }
    }
  }
}

// ---------------------------------------------------------------------------
// Fused 5-way token-mix GEMM, z-loop INSIDE: one block computes the 128x128
// tile for all 5 f's.  C_f = bf16( x + xx * (tm_f + MIXB_f @ W2T_f^T) ).
// A-tile [128][160] staged once (2560 16B chunks); ex/exx hoisted to regs.
// ---------------------------------------------------------------------------
struct Mix5P { const u16* ex; const u16* exx; u16* out[5]; const float* tm[5]; };

__global__ __launch_bounds__(256) void gemm_mix5(
    const u16* __restrict__ Am, const u16* __restrict__ W2T, Mix5P mp)
{
  __shared__ u16 As[128 * 160];   // 40 KB, stride 160
  __shared__ u16 Bs[128 * 32];    // 8 KB
  const int tid = threadIdx.x;
  const int wave = tid >> 6, lane = tid & 63;
  const int wr = wave >> 1, wc = wave & 1;
  const int l16 = lane & 15, kq = lane >> 4;
  const long row0 = (long)blockIdx.x * 128;
  const long col0 = (long)blockIdx.y * 128;

  // stage A-tile [128][160]: 160 u16/row = 20 chunks/row, 2560 chunks total.
  // LDS dest &As[c*8] == r*160 + c8*8 (per-lane contiguous, stride-160 layout)
#pragma unroll
  for (int it = 0; it < 10; it++){
    const int c = tid + it * 256;
    const int r = c / 20, c8 = c - r * 20;
    gload16(Am + (row0 + r) * 256 + c8 * 8, &As[c * 8]);
  }

  // hoisted ex/exx loads: 64 positions, packed (ex lo | exx hi)
  u32 pxx[64];
#pragma unroll
  for (int mi = 0; mi < 4; mi++)
#pragma unroll
    for (int qq = 0; qq < 4; qq++){
      const long r = row0 + wr*64 + mi*16 + kq*4 + qq;
#pragma unroll
      for (int ni = 0; ni < 4; ni++){
        const long c = col0 + wc*64 + ni*16 + l16;
        const u16 a = mp.ex[r * 1024 + c];
        const u16 b = mp.exx[r * 1024 + c];
        pxx[mi*16 + qq*4 + ni] = (u32)a | ((u32)b << 16);
      }
    }

  for (int z = 0; z < 5; z++){
    __syncthreads();
    const u16* B = W2T + z * 32768;
#pragma unroll
    for (int it = 0; it < 2; it++){
      const int c = tid + it * 256;
      gload16(B + (col0 + (c >> 2)) * 32 + (c & 3) * 8, &Bs[c * 8]);
    }
    __syncthreads();
    short8 af[4], bfr[4];
#pragma unroll
    for (int mi = 0; mi < 4; mi++) af[mi]  = *(const short8*)&As[(wr*64 + mi*16 + l16)*160 + z*32 + kq*8];
#pragma unroll
    for (int ni = 0; ni < 4; ni++) bfr[ni] = *(const short8*)&Bs[(wc*64 + ni*16 + l16)*32 + kq*8];
    f32x4 acc[4][4];
#pragma unroll
    for (int i = 0; i < 4; i++)
#pragma unroll
      for (int j = 0; j < 4; j++) acc[i][j] = (f32x4)0.0f;
#pragma unroll
    for (int mi = 0; mi < 4; mi++)
#pragma unroll
      for (int ni = 0; ni < 4; ni++)
        acc[mi][ni] = __builtin_amdgcn_mfma_f32_16x16x32_bf16(af[mi], bfr[ni], acc[mi][ni], 0, 0, 0);

    const float* tm = mp.tm[z];
    float tmv[4];
#pragma unroll
    for (int ni = 0; ni < 4; ni++) tmv[ni] = tm[col0 + wc*64 + ni*16 + l16];
    u16* C = mp.out[z];
#pragma unroll
    for (int mi = 0; mi < 4; mi++){
#pragma unroll
      for (int qq = 0; qq < 4; qq++){
        const long r = row0 + wr*64 + mi*16 + kq*4 + qq;
        u16* crow = C + r * 1024 + col0 + wc*64 + l16;
#pragma unroll
        for (int ni = 0; ni < 4; ni++){
          const u32 pk = pxx[mi*16 + qq*4 + ni];
          const float xc = b2f(LOH(pk));
          const float xx = b2f(HIH(pk));
          crow[ni * 16] = f2b(xc + xx * (tmv[ni] + acc[mi][ni][qq]));
        }
      }
    }
  }
}

// ---------------------------------------------------------------------------
// XM = bf16(x + (xp-x)*tmx);  XBF = bf16(x);  XX = bf16(xp - x)
// ---------------------------------------------------------------------------
__global__ __launch_bounds__(256) void mkxm_k(const float* __restrict__ X,
    const float* __restrict__ tmx, u16* __restrict__ XM,
    u16* __restrict__ XBF, u16* __restrict__ XXo)
{
  const long idx = (long)blockIdx.x * 256 + threadIdx.x;
  const long m = idx >> 8;
  const int c4 = (int)(idx & 255) * 4;
  const float4 x = *(const float4*)(X + m * 1024 + c4);
  float4 p = make_float4(0.f, 0.f, 0.f, 0.f);
  if ((m & 2047) != 0) p = *(const float4*)(X + (m - 1) * 1024 + c4);
  const float4 t = *(const float4*)(tmx + c4);
  ushort4 o;
  o.x = f2b(x.x + (p.x - x.x) * t.x);
  o.y = f2b(x.y + (p.y - x.y) * t.y);
  o.z = f2b(x.z + (p.z - x.z) * t.z);
  o.w = f2b(x.w + (p.w - x.w) * t.w);
  *(ushort4*)(XM + m * 1024 + c4) = o;
  ushort4 ob; ob.x = f2b(x.x); ob.y = f2b(x.y); ob.z = f2b(x.z); ob.w = f2b(x.w);
  *(ushort4*)(XBF + m * 1024 + c4) = ob;
  ushort4 ox; ox.x = f2b(p.x - x.x); ox.y = f2b(p.y - x.y); ox.z = f2b(p.z - x.z); ox.w = f2b(p.w - x.w);
  *(ushort4*)(XXo + m * 1024 + c4) = ox;
}

// ---------------------------------------------------------------------------
// 5 weight casts in one launch (blockIdx.y = which)
// ---------------------------------------------------------------------------
struct Cast5P { const float* s[5]; u16* d[5]; };
__global__ __launch_bounds__(256) void cast5_k(Cast5P cp)
{
  const int w = blockIdx.y;
  const long i = (long)blockIdx.x * 256 + threadIdx.x;
  const float4 v = ((const float4*)cp.s[w])[i];
  ushort4 o; o.x = f2b(v.x); o.y = f2b(v.y); o.z = f2b(v.z); o.w = f2b(v.w);
  ((ushort4*)cp.d[w])[i] = o;
}

// ---------------------------------------------------------------------------
// dst[n][k] = bf16( (n < Ccols) ? src[k][n] : 0 )   dst [dstR][R], idx = n*R+k
// ---------------------------------------------------------------------------
__global__ __launch_bounds__(256) void tpad_k(const float* __restrict__ src,
    u16* __restrict__ dst, int R, int Ccols, long total)
{
  const long idx = (long)blockIdx.x * 256 + threadIdx.x;
  if (idx >= total) return;
  const int k = (int)(idx % R);
  const int n = (int)(idx / R);
  dst[idx] = (n < Ccols) ? f2b(src[(long)k * Ccols + n]) : (u16)0;
}

// ---------------------------------------------------------------------------
// MW2 [5][32][1024] -> W2T [5][1024][32] bf16, one launch
// ---------------------------------------------------------------------------
__global__ __launch_bounds__(256) void tpw2_k(const float* __restrict__ src,
    u16* __restrict__ dst)
{
  const int n = blockIdx.x * 256 + threadIdx.x;    // < 163840
  const int k = n & 31;
  const int col = (n >> 5) & 1023;
  const int f = n >> 15;
  dst[n] = f2b(src[f * 32768 + k * 1024 + col]);
}

// ---------------------------------------------------------------------------
// WKV6 stage 1 (MFMA). Block per (b,h,chunk).
//  M = r̃·k̃ᵀ (masked s<i), Y = M·V + diag·v (bf16 out), A = k̃ᵀ·V, r̃ -> Rg, Pg.
// ---------------------------------------------------------------------------
__global__ __launch_bounds__(256) void wkv_s1(
    u16* __restrict__ Rg, const u16* __restrict__ Kg, const u16* __restrict__ Vg,
    const float* __restrict__ Dg, const float* __restrict__ Ug,
    u16* __restrict__ Yg, float* __restrict__ Ag, float* __restrict__ Pg)
{
  __shared__ u16 RT_[64 * 72];     // r -> r̃  [i][k]
  __shared__ u16 KT_[64 * 72];     // k -> k̃  [s][k]
  __shared__ u16 KTT_[64 * 72];    // k̃ᵀ [k][s]
  __shared__ u16 V_[64 * 72];      // V [s][j]
  __shared__ u16 VT_[64 * 72];     // Vᵀ [j][s]
  __shared__ char UD_[64 * 68 * 4];// D f32 [i][68], then M u16 [i][72]
  __shared__ float us_[64];
  __shared__ float dg4_[256];
  __shared__ float dg_[64];
  float* D_ = (float*)UD_;
  u16*  M_  = (u16*)UD_;

  const int tid = threadIdx.x;
  const int bh = blockIdx.x >> 5, ch = blockIdx.x & 31;
  const int b = bh >> 4, h = bh & 15, cb = h * 64;
  const long rowb = (long)b * 2048 + ch * 64;

  if (tid < 64) us_[tid] = Ug[cb + tid];

  const int iS = tid >> 2, sg = tid & 3;
  // ---- P0: stage r,k,v(,vT),d
  {
    const long go = (rowb + iS) * 1024 + cb + sg * 16;
    uint4 a0 = *(const uint4*)(Rg + go);
    uint4 a1 = *(const uint4*)(Rg + go + 8);
    u32* rd = (u32*)&RT_[iS * 72 + sg * 16];
    rd[0]=a0.x; rd[1]=a0.y; rd[2]=a0.z; rd[3]=a0.w;
    rd[4]=a1.x; rd[5]=a1.y; rd[6]=a1.z; rd[7]=a1.w;
    a0 = *(const uint4*)(Kg + go); a1 = *(const uint4*)(Kg + go + 8);
    u32* kd = (u32*)&KT_[iS * 72 + sg * 16];
    kd[0]=a0.x; kd[1]=a0.y; kd[2]=a0.z; kd[3]=a0.w;
    kd[4]=a1.x; kd[5]=a1.y; kd[6]=a1.z; kd[7]=a1.w;
    a0 = *(const uint4*)(Vg + go); a1 = *(const uint4*)(Vg + go + 8);
    u32* vd = (u32*)&V_[iS * 72 + sg * 16];
    vd[0]=a0.x; vd[1]=a0.y; vd[2]=a0.z; vd[3]=a0.w;
    vd[4]=a1.x; vd[5]=a1.y; vd[6]=a1.z; vd[7]=a1.w;
    const u32 vw[8] = {a0.x,a0.y,a0.z,a0.w,a1.x,a1.y,a1.z,a1.w};
#pragma unroll
    for (int e = 0; e < 8; e++){
      VT_[(sg*16 + 2*e    ) * 72 + iS] = LOH(vw[e]);
      VT_[(sg*16 + 2*e + 1) * 72 + iS] = HIH(vw[e]);
    }
    const float4* dsrc = (const float4*)(Dg + go);
    float4* dd = (float4*)&D_[iS * 68 + sg * 16];
    dd[0]=dsrc[0]; dd[1]=dsrc[1]; dd[2]=dsrc[2]; dd[3]=dsrc[3];
  }
  __syncthreads();
  // ---- P0b: diag partials with RAW r,k
  {
    const int i = tid & 63, q = tid >> 6;
    const u32* rr = (const u32*)&RT_[i * 72 + q * 16];
    const u32* kr = (const u32*)&KT_[i * 72 + q * 16];
    const float* up = &us_[q * 16];
    float ds = 0.0f;
#pragma unroll
    for (int e = 0; e < 8; e++){
      ds += b2f(LOH(rr[e])) * up[2*e]   * b2f(LOH(kr[e]));
      ds += b2f(HIH(rr[e])) * up[2*e+1] * b2f(HIH(kr[e]));
    }
    dg4_[i * 4 + q] = ds;
  }
  __syncthreads();
  // ---- P0c: prefix decay; RT->r̃, KT->k̃ (and KTT); diag finalize; Pg
  if (tid < 64){
    const int k = tid;
    dg_[k] = dg4_[k*4] + dg4_[k*4+1] + dg4_[k*4+2] + dg4_[k*4+3];
    float pz = 1.0f;
#pragma unroll 4
    for (int i = 0; i < 64; i++){
      const float d = D_[i * 68 + k];
      const int ro = i * 72 + k;
      RT_[ro] = f2b(b2f(RT_[ro]) * pz);
      pz *= d;
      const u16 kb = f2b(b2f(KT_[ro]) * (1.0f / pz));
      KT_[ro] = kb;
      KTT_[k * 72 + i] = kb;
    }
    Pg[((long)bh * 32 + ch) * 64 + k] = pz;
  }
  __syncthreads();
  // ---- writeback r̃ to Rg
  {
    const u32* rr = (const u32*)&RT_[iS * 72 + sg * 16];
    u32* out = (u32*)(Rg + (rowb + iS) * 1024 + cb + sg * 16);
#pragma unroll
    for (int e = 0; e < 8; e++) out[e] = rr[e];
  }
  const int wave = tid >> 6, lane = tid & 63;
  const int wr = wave >> 1, wc = wave & 1;
  const int l16 = lane & 15, kq = lane >> 4;
  // ---- P2: M = r̃·k̃ᵀ, mask s<i, store bf16 to M_
  {
    f32x4 acc[2][2];
#pragma unroll
    for (int a = 0; a < 2; a++)
#pragma unroll
      for (int c = 0; c < 2; c++) acc[a][c] = (f32x4)0.0f;
#pragma unroll
    for (int ks = 0; ks < 2; ks++){
      short8 af[2], bf[2];
#pragma unroll
      for (int mi = 0; mi < 2; mi++) af[mi] = *(const short8*)&RT_[(wr*32 + mi*16 + l16)*72 + ks*32 + kq*8];
#pragma unroll
      for (int ni = 0; ni < 2; ni++) bf[ni] = *(const short8*)&KT_[(wc*32 + ni*16 + l16)*72 + ks*32 + kq*8];
#pragma unroll
      for (int mi = 0; mi < 2; mi++)
#pragma unroll
        for (int ni = 0; ni < 2; ni++)
          acc[mi][ni] = __builtin_amdgcn_mfma_f32_16x16x32_bf16(af[mi], bf[ni], acc[mi][ni], 0, 0, 0);
    }
    __syncthreads();    // D_ dead; M_ union becomes valid
#pragma unroll
    for (int mi = 0; mi < 2; mi++)
#pragma unroll
      for (int ni = 0; ni < 2; ni++)
#pragma unroll
        for (int qq = 0; qq < 4; qq++){
          const int ii = wr*32 + mi*16 + kq*4 + qq;
          const int ss = wc*32 + ni*16 + l16;
          M_[ii * 72 + ss] = f2b(ss < ii ? acc[mi][ni][qq] : 0.0f);
        }
  }
  __syncthreads();
  // ---- P3+P4: Y = M·V + diag·v ; A = k̃ᵀ·V
  {
    f32x4 accY[2][2], accA[2][2];
#pragma unroll
    for (int a = 0; a < 2; a++)
#pragma unroll
      for (int c = 0; c < 2; c++){ accY[a][c] = (f32x4)0.0f; accA[a][c] = (f32x4)0.0f; }
#pragma unroll
    for (int ks = 0; ks < 2; ks++){
      short8 am[2], ak[2], bv[2];
#pragma unroll
      for (int mi = 0; mi < 2; mi++){
        am[mi] = *(const short8*)&M_[(wr*32 + mi*16 + l16)*72 + ks*32 + kq*8];
        ak[mi] = *(const short8*)&KTT_[(wr*32 + mi*16 + l16)*72 + ks*32 + kq*8];
      }
#pragma unroll
      for (int ni = 0; ni < 2; ni++) bv[ni] = *(const short8*)&VT_[(wc*32 + ni*16 + l16)*72 + ks*32 + kq*8];
#pragma unroll
      for (int mi = 0; mi < 2; mi++)
#pragma unroll
        for (int ni = 0; ni < 2; ni++){
          accY[mi][ni] = __builtin_amdgcn_mfma_f32_16x16x32_bf16(am[mi], bv[ni], accY[mi][ni], 0, 0, 0);
          accA[mi][ni] = __builtin_amdgcn_mfma_f32_16x16x32_bf16(ak[mi], bv[ni], accA[mi][ni], 0, 0, 0);
        }
    }
    float* abase = Ag + ((long)bh * 32 + ch) * 4096;
#pragma unroll
    for (int mi = 0; mi < 2; mi++)
#pragma unroll
      for (int qq = 0; qq < 4; qq++){
        const int ii = wr*32 + mi*16 + kq*4 + qq;
        u16* yrow = Yg + (rowb + ii) * 1024 + cb;
        float* arow = abase + ii * 64;
#pragma unroll
        for (int ni = 0; ni < 2; ni++){
          const int jj = wc*32 + ni*16 + l16;
          const float yv = accY[mi][ni][qq] + dg_[ii] * b2f(V_[ii * 72 + jj]);
          yrow[jj] = f2b(yv);
          arow[jj] = accA[mi][ni][qq];
        }
      }
  }
}

// ---------------------------------------------------------------------------
// WKV6 stage 2 — inter-chunk recurrence S_{c+1} = ps_c*(S_c + A_c).
// ---------------------------------------------------------------------------
__global__ __launch_bounds__(256) void wkv_s2(
    const float* __restrict__ Ag, const float* __restrict__ Pg, float* __restrict__ Sg)
{
  const int tid = threadIdx.x;
  const int bh = blockIdx.x >> 2, kq = blockIdx.x & 3;
  const int kk = tid >> 4, jo = tid & 15;
  const int krow = kq * 16 + kk;
  const long base = (long)bh * 32;
  float4 S = make_float4(0.f, 0.f, 0.f, 0.f);
  for (int c = 0; c < 32; c++){
    const long mo = (base + c) * 4096 + krow * 64 + jo * 4;
    *(float4*)(Sg + mo) = S;
    const float4 a = *(const float4*)(Ag + mo);
    const float ps = Pg[(base + c) * 64 + krow];
    S.x = ps * (S.x + a.x); S.y = ps * (S.y + a.y);
    S.z = ps * (S.z + a.z); S.w = ps * (S.w + a.w);
  }
}

// ---------------------------------------------------------------------------
// WKV6 stage 3 — cross term: Yg += rt~ . S_chunkstart (bf16 RMW).
// ---------------------------------------------------------------------------
__global__ __launch_bounds__(256) void wkv_s3(
    const u16* __restrict__ Rtg, const float* __restrict__ Sg, u16* __restrict__ Yg)
{
  __shared__ float Ss[4096];        // [k][j]
  __shared__ u16 RTs[64 * 66];
  const int tid = threadIdx.x;
  const int bh = blockIdx.x >> 5, ch = blockIdx.x & 31;
  if (ch == 0) return;
  const int b = bh >> 4, h = bh & 15, cb = h * 64;
  const long rowb = (long)b * 2048 + ch * 64;

  {
    const float4* sp = (const float4*)(Sg + ((long)bh * 32 + ch) * 4096);
    float4* sd = (float4*)Ss;
#pragma unroll
    for (int e = 0; e < 4; e++) sd[tid + e * 256] = sp[tid + e * 256];
  }
  {
    const int iS = tid >> 2, sg4 = tid & 3;
    const u32* src = (const u32*)(Rtg + (rowb + iS) * 1024 + cb + sg4 * 16);
    u32* dst = (u32*)&RTs[iS * 66 + sg4 * 16];
#pragma unroll
    for (int e = 0; e < 8; e++) dst[e] = src[e];
  }
  __syncthreads();

  const int i_ = tid & 63, q = tid >> 6, jb = q * 16;
  float rt[64];
  {
    const u32* rr = (const u32*)&RTs[i_ * 66];
#pragma unroll
    for (int kk = 0; kk < 32; kk++){
      const u32 u = rr[kk];
      rt[2*kk] = b2f(LOH(u)); rt[2*kk+1] = b2f(HIH(u));
    }
  }
  u16* yo = Yg + (rowb + i_) * 1024 + cb + jb;
  float y[16];
  {
    const u32* yp = (const u32*)yo;
#pragma unroll
    for (int j2 = 0; j2 < 8; j2++){
      const u32 u = yp[j2];
      y[2*j2] = b2f(LOH(u)); y[2*j2+1] = b2f(HIH(u));
    }
  }
#pragma unroll
  for (int k = 0; k < 64; k++){
    const float rk = rt[k];
    const float4* sr = (const float4*)&Ss[k * 64 + jb];
#pragma unroll
    for (int j4 = 0; j4 < 4; j4++){
      const float4 sv = sr[j4];
      y[4*j4+0] += rk*sv.x; y[4*j4+1] += rk*sv.y; y[4*j4+2] += rk*sv.z; y[4*j4+3] += rk*sv.w;
    }
  }
  {
    u32* yp = (u32*)yo;
#pragma unroll
    for (int j2 = 0; j2 < 8; j2++)
      yp[j2] = (u32)f2b(y[2*j2]) | ((u32)f2b(y[2*j2+1]) << 16);
  }
}

// ---------------------------------------------------------------------------
// GroupNorm over each head's 64 channels, then * g   (one block per bt row)
// ---------------------------------------------------------------------------
__global__ __launch_bounds__(256) void gnorm_k(const u16* __restrict__ Y,
    const u16* __restrict__ G, const float* __restrict__ lng,
    const float* __restrict__ lnb, u16* __restrict__ Z)
{
  const long row = blockIdx.x;
  const int tid = threadIdx.x;
  const int hh = tid >> 4, l = tid & 15;
  const int c = hh * 64 + l * 4;
  const u32* yp = (const u32*)(Y + row * 1024 + c);
  const u32 y01 = yp[0], y23 = yp[1];
  const float vv[4] = {b2f(LOH(y01)), b2f(HIH(y01)), b2f(LOH(y23)), b2f(HIH(y23))};
  float s = vv[0] + vv[1] + vv[2] + vv[3];
  float sq = vv[0]*vv[0] + vv[1]*vv[1] + vv[2]*vv[2] + vv[3]*vv[3];
#pragma unroll
  for (int off = 1; off < 16; off <<= 1){ s += __shfl_xor(s, off); sq += __shfl_xor(sq, off); }
  const float mean = s * 0.015625f;
  const float var = sq * 0.015625f - mean * mean;
  const float rstd = rsqrtf(var + 6.4e-4f);   // eps = 1e-5 * 64
  const uint2 gg = *(const uint2*)(G + row * 1024 + c);
  const float4 lg = *(const float4*)(lng + c);
  const float4 lb = *(const float4*)(lnb + c);
  const float lgs[4] = {lg.x, lg.y, lg.z, lg.w};
  const float lbs[4] = {lb.x, lb.y, lb.z, lb.w};
  const u32 gs[2] = {gg.x, gg.y};
  ushort4 o;
  u16* op = (u16*)&o;
#pragma unroll
  for (int e = 0; e < 4; e++){
    const float gv = b2f((e & 1) ? HIH(gs[e >> 1]) : LOH(gs[e >> 1]));
    op[e] = f2b(((vv[e] - mean) * rstd * lgs[e] + lbs[e]) * gv);
  }
  *(ushort4*)(Z + row * 1024 + c) = o;
}

// ---------------------------------------------------------------------------
extern "C" void kernel_launch(void* const* d_in, const int* in_sizes, int n_in,
                              void* d_out, int out_size, void* d_ws, size_t ws_size,
                              hipStream_t stream)
{
  (void)in_sizes; (void)n_in; (void)out_size; (void)ws_size;
  const float* X    = (const float*)d_in[0];
  const float* TMX  = (const float*)d_in[1];
  const float* TMW  = (const float*)d_in[2];
  const float* TMK  = (const float*)d_in[3];
  const float* TMV  = (const float*)d_in[4];
  const float* TMR  = (const float*)d_in[5];
  const float* TMG  = (const float*)d_in[6];
  const float* MW1  = (const float*)d_in[7];
  const float* MW2  = (const float*)d_in[8];
  const float* TD   = (const float*)d_in[9];
  const float* TDW1 = (const float*)d_in[10];
  const float* TDW2 = (const float*)d_in[11];
  const float* U    = (const float*)d_in[12];
  const float* WR   = (const float*)d_in[13];
  const float* WK   = (const float*)d_in[14];
  const float* WV   = (const float*)d_in[15];
  const float* WG   = (const float*)d_in[16];
  const float* WO   = (const float*)d_in[17];
  const float* LNG  = (const float*)d_in[18];
  const float* LNB  = (const float*)d_in[19];

  char* ws = (char*)d_ws;
  const size_t SLOT = 16777216ULL;     // B*T*C bf16 bytes
  u16* S1 = (u16*)(ws + 0 * SLOT);     // XM  -> Rb (-> rt~)
  u16* S2 = (u16*)(ws + 1 * SLOT);     // XW  -> Y (bf16)
  u16* S3 = (u16*)(ws + 2 * SLOT);     // XK
  u16* S4 = (u16*)(ws + 3 * SLOT);     // XV  -> Z
  u16* S5 = (u16*)(ws + 4 * SLOT);     // XR  -> DEC lo
  u16* S6 = (u16*)(ws + 5 * SLOT);     // XG  -> DEC hi
  u16* S7 = (u16*)(ws + 6 * SLOT);     // XBF -> Kb -> Sg lo
  u16* S8 = (u16*)(ws + 7 * SLOT);     // XX  -> Vb -> Sg hi
  u16* S9 = (u16*)(ws + 8 * SLOT);     // Gb
  char* p = ws + 9 * SLOT;
  auto alloc = [&](size_t bytes) -> void* {
    void* q = p; p += (bytes + 255) & ~(size_t)255; return q;
  };
  u16* MIXB = (u16*)alloc(8192ULL * 256 * 2);
  u16* Hb   = (u16*)alloc(8192ULL * 128 * 2);
  u16* W1T  = (u16*)alloc(256ULL * 1024 * 2);
  u16* W2T  = (u16*)alloc(5ULL * 1024 * 32 * 2);
  u16* TW1T = (u16*)alloc(128ULL * 1024 * 2);
  u16* TW2T = (u16*)alloc(1024ULL * 64 * 2);
  u16* WRb  = (u16*)alloc(1048576ULL * 2);
  u16* WKb  = (u16*)alloc(1048576ULL * 2);
  u16* WVb  = (u16*)alloc(1048576ULL * 2);
  u16* WGb  = (u16*)alloc(1048576ULL * 2);
  u16* WOb  = (u16*)alloc(1048576ULL * 2);
  float* Ab = (float*)alloc(33554432ULL);   // [bh][c][64][64] f32
  float* Pg = (float*)alloc(524288ULL);     // [bh][c][64] f32

  u16*   XM = S1; u16* XW = S2; u16* XK = S3; u16* XV = S4; u16* XR = S5; u16* XG = S6;
  u16*   XBF = S7; u16* XX = S8;
  u16*   Rb = S1; u16* Kb = S7; u16* Vb = S8; u16* Gb = S9;
  u16*   Y   = S2;            // bf16 now (xw dead after Hb gemm)
  float* DEC = (float*)S5;    // spans S5+S6 (xr,xg dead after gemm4)
  float* Sg  = (float*)S7;    // spans S7+S8 (kb,vb dead after s1)
  u16*   Z   = S4;            // xv dead

  // weight casts / transposes (f32 -> bf16, [N][K] K-contiguous)
  Cast5P cp;
  cp.s[0]=WR; cp.s[1]=WK; cp.s[2]=WV; cp.s[3]=WG; cp.s[4]=WO;
  cp.d[0]=WRb; cp.d[1]=WKb; cp.d[2]=WVb; cp.d[3]=WGb; cp.d[4]=WOb;
  cast5_k<<<dim3(1024, 5), 256, 0, stream>>>(cp);
  tpad_k<<<1024, 256, 0, stream>>>(MW1, W1T, 1024, 160, 256LL * 1024);
  tpw2_k<<<640, 256, 0, stream>>>(MW2, W2T);
  tpad_k<<<512, 256, 0, stream>>>(TDW1, TW1T, 1024, 64, 128LL * 1024);
  tpad_k<<<256, 256, 0, stream>>>(TDW2, TW2T, 64, 1024, 1024LL * 64);

  // XM / XBF / XX
  mkxm_k<<<8192, 256, 0, stream>>>(X, TMX, XM, XBF, XX);

  // mix160 = tanh(XM @ maa_w1)        [8192,256(pad)]
  gemm_bt<1><<<dim3(64, 2), 256, 0, stream>>>(XM, 1024, W1T, 1024, MIXB, 256, 1024, nullptr);

  // x{w,k,v,r,g} = x + xx*(tm + mix_f @ maa_w2_f)   — one launch, z-loop inside
  Mix5P mp;
  mp.ex = XBF; mp.exx = XX;
  mp.out[0]=XW; mp.out[1]=XK; mp.out[2]=XV; mp.out[3]=XR; mp.out[4]=XG;
  mp.tm[0]=TMW; mp.tm[1]=TMK; mp.tm[2]=TMV; mp.tm[3]=TMR; mp.tm[4]=TMG;
  gemm_mix5<<<dim3(64, 8), 256, 0, stream>>>(MIXB, W2T, mp);

  // r, k, v, g — fused (Rb over XM; Kb/Vb over XBF/XX — all dead)
  G4P gp;
  gp.A[0]=XR; gp.A[1]=XK; gp.A[2]=XV; gp.A[3]=XG;
  gp.B[0]=WRb; gp.B[1]=WKb; gp.B[2]=WVb; gp.B[3]=WGb;
  gp.C[0]=Rb; gp.C[1]=Kb; gp.C[2]=Vb; gp.C[3]=Gb;
  gemm4_k<<<dim3(64, 8, 4), 256, 0, stream>>>(gp);

  // h = tanh(xw @ td_w1);  decay = exp(-exp(time_decay + h @ td_w2))
  gemm_bt<1><<<dim3(64, 1), 256, 0, stream>>>(XW, 1024, TW1T, 1024, Hb, 128, 1024, nullptr);
  gemm_bt<3><<<dim3(64, 8), 256, 0, stream>>>(Hb, 128, TW2T, 64, DEC, 1024, 64, TD);

  // WKV6 chunk-parallel scan (Y bf16)
  wkv_s1<<<2048, 256, 0, stream>>>(Rb, Kb, Vb, DEC, U, Y, Ab, Pg);
  wkv_s2<<<256, 256, 0, stream>>>(Ab, Pg, Sg);
  wkv_s3<<<2048, 256, 0, stream>>>(Rb, Sg, Y);

  // GroupNorm(y)*g -> z
  gnorm_k<<<8192, 256, 0, stream>>>(Y, Gb, LNG, LNB, Z);

  // out = z @ Wo^T   (f32 out)
  gemm_bt<5><<<dim3(64, 8), 256, 0, stream>>>(Z, 1024, WOb, 1024, (float*)d_out, 1024, 1024, nullptr);
}